// Round 3
// baseline (600.460 us; speedup 1.0000x reference)
//
#include <hip/hip_runtime.h>

#define TB 256
#define NGRP 8            // XCDs on MI355X; blockIdx%8 round-robins across XCDs
#define SCAN_T 256
#define SCAN_NPT 2
#define SCAN_NPB (SCAN_T * SCAN_NPT)

typedef int    i4v __attribute__((ext_vector_type(4)));
typedef float  f4v __attribute__((ext_vector_type(4)));
typedef _Float16 h4v __attribute__((ext_vector_type(4)));

static __device__ __forceinline__ float leaky(float x) {
  return x > 0.f ? x : 0.2f * x;
}

// ---------------- CSR build ----------------

// XCD-ranged histogram: group g only touches deg[lo,hi) -> atomics stay in one L2.
// NT int4 loads keep the 8x dstA re-read from polluting L2.
__global__ void k_hist_r(const int* __restrict__ dstA, int* __restrict__ deg, int E, int R) {
  const int g = blockIdx.x & (NGRP - 1);
  const int lb = blockIdx.x / NGRP;
  const int nbg = gridDim.x / NGRP;
  const int lo = g * R, hi = lo + R;
  const int stride = nbg * blockDim.x;
  const int E4 = E >> 2;
  const i4v* d4 = reinterpret_cast<const i4v*>(dstA);
  for (int i = lb * blockDim.x + threadIdx.x; i < E4; i += stride) {
    i4v d = __builtin_nontemporal_load(&d4[i]);
#pragma unroll
    for (int k = 0; k < 4; ++k) {
      int dd = d[k];
      if (dd >= lo && dd < hi) atomicAdd(&deg[dd], 1);
    }
  }
  if (lb == 0) {  // tail (E % 4), every group filters by its range
    int t = E4 * 4 + threadIdx.x;
    if (t < E) {
      int dd = dstA[t];
      if (dd >= lo && dd < hi) atomicAdd(&deg[dd], 1);
    }
  }
}

// per-block partial sums of deg
__global__ void k_scan1(const int* __restrict__ deg, int* __restrict__ part, int N) {
  __shared__ int red[SCAN_T];
  const int t = threadIdx.x;
  const int base = blockIdx.x * SCAN_NPB + t * SCAN_NPT;
  int s = 0;
#pragma unroll
  for (int i = 0; i < SCAN_NPT; ++i) {
    int idx = base + i;
    if (idx < N) s += deg[idx];
  }
  red[t] = s;
  __syncthreads();
  for (int off = SCAN_T / 2; off > 0; off >>= 1) {
    if (t < off) red[t] += red[t + off];
    __syncthreads();
  }
  if (t == 0) part[blockIdx.x] = red[0];
}

// single-block exclusive scan of partials (nb <= 1024)
__global__ void k_scan2(int* __restrict__ part, int nb) {
  __shared__ int sh[1024];
  const int t = threadIdx.x;
  sh[t] = (t < nb) ? part[t] : 0;
  __syncthreads();
  for (int off = 1; off < 1024; off <<= 1) {
    int v = (t >= off) ? sh[t - off] : 0;
    __syncthreads();
    sh[t] += v;
    __syncthreads();
  }
  if (t < nb) part[t] = (t == 0) ? 0 : sh[t - 1];
}

// per-block exclusive scan + offset -> rowStart, cursor
__global__ void k_scan3(const int* __restrict__ deg, const int* __restrict__ part,
                        int* __restrict__ rowStart, int* __restrict__ cursor, int N) {
  __shared__ int sh[SCAN_T];
  const int t = threadIdx.x;
  const int base = blockIdx.x * SCAN_NPB + t * SCAN_NPT;
  int v[SCAN_NPT];
  int s = 0;
#pragma unroll
  for (int i = 0; i < SCAN_NPT; ++i) {
    int idx = base + i;
    v[i] = (idx < N) ? deg[idx] : 0;
    s += v[i];
  }
  sh[t] = s;
  __syncthreads();
  for (int off = 1; off < SCAN_T; off <<= 1) {
    int u = (t >= off) ? sh[t - off] : 0;
    __syncthreads();
    sh[t] += u;
    __syncthreads();
  }
  int excl = ((t == 0) ? 0 : sh[t - 1]) + part[blockIdx.x];
#pragma unroll
  for (int i = 0; i < SCAN_NPT; ++i) {
    int idx = base + i;
    if (idx < N) {
      rowStart[idx] = excl;
      cursor[idx] = excl;
      excl += v[i];
    }
  }
}

// XCD-ranged fill with NT streaming reads: group g's cursor+colIdx region
// (~1.7 MB) stays resident in its L2 because the srcA/dstA streams bypass
// cache retention -> each colIdx line written back ~once.
__global__ void k_fill_r(const int* __restrict__ srcA, const int* __restrict__ dstA,
                         int* __restrict__ cursor, int* __restrict__ colIdx, int E, int R) {
  const int g = blockIdx.x & (NGRP - 1);
  const int lb = blockIdx.x / NGRP;
  const int nbg = gridDim.x / NGRP;
  const int lo = g * R, hi = lo + R;
  const int stride = nbg * blockDim.x;
  const int E4 = E >> 2;
  const i4v* d4 = reinterpret_cast<const i4v*>(dstA);
  const i4v* s4 = reinterpret_cast<const i4v*>(srcA);
  for (int i = lb * blockDim.x + threadIdx.x; i < E4; i += stride) {
    i4v d = __builtin_nontemporal_load(&d4[i]);
    bool hit0 = d[0] >= lo && d[0] < hi;
    bool hit1 = d[1] >= lo && d[1] < hi;
    bool hit2 = d[2] >= lo && d[2] < hi;
    bool hit3 = d[3] >= lo && d[3] < hi;
    if (hit0 | hit1 | hit2 | hit3) {
      i4v sv = __builtin_nontemporal_load(&s4[i]);
      if (hit0) { int pos = atomicAdd(&cursor[d[0]], 1); colIdx[pos] = sv[0]; }
      if (hit1) { int pos = atomicAdd(&cursor[d[1]], 1); colIdx[pos] = sv[1]; }
      if (hit2) { int pos = atomicAdd(&cursor[d[2]], 1); colIdx[pos] = sv[2]; }
      if (hit3) { int pos = atomicAdd(&cursor[d[3]], 1); colIdx[pos] = sv[3]; }
    }
  }
  if (lb == 0) {  // tail
    int t = E4 * 4 + threadIdx.x;
    if (t < E) {
      int dd = dstA[t];
      if (dd >= lo && dd < hi) {
        int pos = atomicAdd(&cursor[dd], 1);
        colIdx[pos] = srcA[t];
      }
    }
  }
}

// ---------------- node transform: h = x@W (fp16 out), alpha_src/dst (fp32) ----------------

template <int IN, int H, int C>
__global__ void k_node(const float* __restrict__ xin, const float* __restrict__ W,
                       const float* __restrict__ a_src, const float* __restrict__ a_dst,
                       _Float16* __restrict__ hout, float* __restrict__ as_,
                       float* __restrict__ ad_, int N) {
  constexpr int OUT = H * C;
  __shared__ float Ws[IN * OUT];
  __shared__ float As[OUT], Ad[OUT];
  for (int i = threadIdx.x; i < IN * OUT; i += blockDim.x) Ws[i] = W[i];
  if (threadIdx.x < OUT) {
    As[threadIdx.x] = a_src[threadIdx.x];
    Ad[threadIdx.x] = a_dst[threadIdx.x];
  }
  __syncthreads();
  int n = blockIdx.x * blockDim.x + threadIdx.x;
  if (n >= N) return;
  float acc[OUT];
#pragma unroll
  for (int j = 0; j < OUT; ++j) acc[j] = 0.f;
  const f4v* x4 = reinterpret_cast<const f4v*>(xin + (size_t)n * IN);
#pragma unroll
  for (int k4 = 0; k4 < IN / 4; ++k4) {
    f4v xv = __builtin_nontemporal_load(&x4[k4]);
#pragma unroll
    for (int j = 0; j < OUT; ++j) {
      acc[j] += xv[0] * Ws[(4 * k4 + 0) * OUT + j];
      acc[j] += xv[1] * Ws[(4 * k4 + 1) * OUT + j];
      acc[j] += xv[2] * Ws[(4 * k4 + 2) * OUT + j];
      acc[j] += xv[3] * Ws[(4 * k4 + 3) * OUT + j];
    }
  }
  h4v* h4 = reinterpret_cast<h4v*>(hout + (size_t)n * OUT);
#pragma unroll
  for (int j4 = 0; j4 < OUT / 4; ++j4) {
    h4v v;
    v[0] = (_Float16)acc[4 * j4 + 0];
    v[1] = (_Float16)acc[4 * j4 + 1];
    v[2] = (_Float16)acc[4 * j4 + 2];
    v[3] = (_Float16)acc[4 * j4 + 3];
    h4[j4] = v;
  }
#pragma unroll
  for (int hh = 0; hh < H; ++hh) {
    float ss = 0.f, dd = 0.f;
#pragma unroll
    for (int c = 0; c < C; ++c) {
      ss += acc[hh * C + c] * As[hh * C + c];
      dd += acc[hh * C + c] * Ad[hh * C + c];
    }
    as_[n * H + hh] = ss;
    ad_[n * H + hh] = dd;
  }
}

// ---------------- edge aggregation: L lanes per node, fp16 half4 per lane ----------------

template <int H, int C, int L, bool RELU>
__global__ void k_edge_ml(const int* __restrict__ rowStart, const int* __restrict__ deg,
                          const int* __restrict__ colIdx, const _Float16* __restrict__ hfeat,
                          const float* __restrict__ as_, const float* __restrict__ ad_,
                          const float* __restrict__ bias, float* __restrict__ out, int N) {
  constexpr int OUT = H * C;
  static_assert(OUT == L * 4, "lane layout");
  int tid = blockIdx.x * blockDim.x + threadIdx.x;
  int n = tid / L;
  int j = tid & (L - 1);
  if (n >= N) return;
  const int hh = (j * 4) / C;  // head owning this lane's chunk
  float adv = ad_[n * H + hh];
  float m = leaky(as_[n * H + hh] + adv);  // self-loop term
  float s = 1.f;
  h4v a0 = reinterpret_cast<const h4v*>(hfeat + (size_t)n * OUT)[j];
  float acc0 = (float)a0[0], acc1 = (float)a0[1], acc2 = (float)a0[2], acc3 = (float)a0[3];
  const int start = rowStart[n];
  const int cnt = deg[n];
  for (int i = 0; i < cnt; ++i) {
    int src = __builtin_nontemporal_load(&colIdx[start + i]);
    h4v hv = reinterpret_cast<const h4v*>(hfeat + (size_t)src * OUT)[j];
    float e = leaky(as_[src * H + hh] + adv);
    float nm = fmaxf(m, e);
    float f = __expf(m - nm);
    float p = __expf(e - nm);
    m = nm;
    s = s * f + p;
    acc0 = acc0 * f + p * (float)hv[0];
    acc1 = acc1 * f + p * (float)hv[1];
    acc2 = acc2 * f + p * (float)hv[2];
    acc3 = acc3 * f + p * (float)hv[3];
  }
  float inv = 1.f / (s + 1e-16f);
  float4 bb = reinterpret_cast<const float4*>(bias)[j];
  float4 o;
  o.x = acc0 * inv + bb.x;
  o.y = acc1 * inv + bb.y;
  o.z = acc2 * inv + bb.z;
  o.w = acc3 * inv + bb.w;
  if (RELU) {
    o.x = fmaxf(o.x, 0.f);
    o.y = fmaxf(o.y, 0.f);
    o.z = fmaxf(o.z, 0.f);
    o.w = fmaxf(o.w, 0.f);
  }
  reinterpret_cast<float4*>(out + (size_t)n * OUT)[j] = o;
}

// ---------------- layer-3 edge aggregation + fused classifier ----------------

__global__ void k_edge3(const int* __restrict__ rowStart, const int* __restrict__ deg,
                        const int* __restrict__ colIdx, const _Float16* __restrict__ hfeat,
                        const float* __restrict__ as_, const float* __restrict__ ad_,
                        const float* __restrict__ b3, const float* __restrict__ Wc,
                        const float* __restrict__ bc, float* __restrict__ out, int N) {
  int n = blockIdx.x * blockDim.x + threadIdx.x;
  if (n >= N) return;
  float adv = ad_[n];
  float m = leaky(as_[n] + adv);
  float s = 1.f;
  h4v hn = reinterpret_cast<const h4v*>(hfeat)[n];
  float acc0 = (float)hn[0], acc1 = (float)hn[1], acc2 = (float)hn[2], acc3 = (float)hn[3];
  const int start = rowStart[n];
  const int cnt = deg[n];
  for (int i = 0; i < cnt; ++i) {
    int src = __builtin_nontemporal_load(&colIdx[start + i]);
    h4v hv = reinterpret_cast<const h4v*>(hfeat)[src];
    float e = leaky(as_[src] + adv);
    float nm = fmaxf(m, e);
    float f = __expf(m - nm);
    float p = __expf(e - nm);
    m = nm;
    s = s * f + p;
    acc0 = acc0 * f + p * (float)hv[0];
    acc1 = acc1 * f + p * (float)hv[1];
    acc2 = acc2 * f + p * (float)hv[2];
    acc3 = acc3 * f + p * (float)hv[3];
  }
  float inv = 1.f / (s + 1e-16f);
  float o0 = acc0 * inv + b3[0];
  float o1 = acc1 * inv + b3[1];
  float o2 = acc2 * inv + b3[2];
  float o3 = acc3 * inv + b3[3];
  float r0 = o0 * Wc[0] + o1 * Wc[2] + o2 * Wc[4] + o3 * Wc[6] + bc[0];
  float r1 = o0 * Wc[1] + o1 * Wc[3] + o2 * Wc[5] + o3 * Wc[7] + bc[1];
  out[(size_t)n * 2 + 0] = r0;
  out[(size_t)n * 2 + 1] = r1;
}

// ---------------- launch ----------------

extern "C" void kernel_launch(void* const* d_in, const int* in_sizes, int n_in,
                              void* d_out, int out_size, void* d_ws, size_t ws_size,
                              hipStream_t stream) {
  const float* x    = (const float*)d_in[0];
  const int*   ei   = (const int*)d_in[1];
  const float* W1   = (const float*)d_in[2];
  const float* as1w = (const float*)d_in[3];
  const float* ad1w = (const float*)d_in[4];
  const float* b1   = (const float*)d_in[5];
  const float* W2   = (const float*)d_in[6];
  const float* as2w = (const float*)d_in[7];
  const float* ad2w = (const float*)d_in[8];
  const float* b2   = (const float*)d_in[9];
  const float* W3   = (const float*)d_in[10];
  const float* as3w = (const float*)d_in[11];
  const float* ad3w = (const float*)d_in[12];
  const float* b3   = (const float*)d_in[13];
  const float* Wc   = (const float*)d_in[14];
  const float* bc   = (const float*)d_in[15];
  float* out = (float*)d_out;

  const int N = in_sizes[0] / 128;
  const int E = in_sizes[1] / 2;
  const int* srcA = ei;
  const int* dstA = ei + E;

  char* p = (char*)d_ws;
  auto alloc = [&](size_t bytes) -> void* {
    void* r = (void*)p;
    p += (bytes + 255) & ~(size_t)255;
    return r;
  };
  int* deg      = (int*)alloc((size_t)N * 4);
  int* rowStart = (int*)alloc((size_t)N * 4);
  int* cursor   = (int*)alloc((size_t)N * 4);
  int* part     = (int*)alloc(1024 * 4);
  int* colIdx   = (int*)alloc((size_t)E * 4);
  _Float16* h1 = (_Float16*)alloc((size_t)N * 16 * 2);
  float* as1 = (float*)alloc((size_t)N * 2 * 4);
  float* ad1 = (float*)alloc((size_t)N * 2 * 4);
  float* o1  = (float*)alloc((size_t)N * 16 * 4);
  _Float16* h2 = (_Float16*)alloc((size_t)N * 8 * 2);
  float* as2 = (float*)alloc((size_t)N * 2 * 4);
  float* ad2 = (float*)alloc((size_t)N * 2 * 4);
  float* o2  = (float*)alloc((size_t)N * 8 * 4);
  _Float16* h3 = (_Float16*)alloc((size_t)N * 4 * 2);
  float* as3 = (float*)alloc((size_t)N * 4);
  float* ad3 = (float*)alloc((size_t)N * 4);

  hipMemsetAsync(deg, 0, (size_t)N * 4, stream);

  const int nb = (N + TB - 1) / TB;
  const int sb = (N + SCAN_NPB - 1) / SCAN_NPB;   // <= 1024
  const int R  = (N + NGRP - 1) / NGRP;

  k_hist_r<<<1024, TB, 0, stream>>>(dstA, deg, E, R);
  k_scan1<<<sb, SCAN_T, 0, stream>>>(deg, part, N);
  k_scan2<<<1, 1024, 0, stream>>>(part, sb);
  k_scan3<<<sb, SCAN_T, 0, stream>>>(deg, part, rowStart, cursor, N);
  k_fill_r<<<1024, TB, 0, stream>>>(srcA, dstA, cursor, colIdx, E, R);

  // layer 1: in=128, H=2, C=8 (4 lanes/node)
  k_node<128, 2, 8><<<nb, TB, 0, stream>>>(x, W1, as1w, ad1w, h1, as1, ad1, N);
  k_edge_ml<2, 8, 4, true><<<(N * 4 + TB - 1) / TB, TB, 0, stream>>>(rowStart, deg, colIdx, h1, as1, ad1, b1, o1, N);

  // layer 2: in=16, H=2, C=4 (2 lanes/node)
  k_node<16, 2, 4><<<nb, TB, 0, stream>>>(o1, W2, as2w, ad2w, h2, as2, ad2, N);
  k_edge_ml<2, 4, 2, true><<<(N * 2 + TB - 1) / TB, TB, 0, stream>>>(rowStart, deg, colIdx, h2, as2, ad2, b2, o2, N);

  // layer 3: in=8, H=1, C=4 + fused classifier
  k_node<8, 1, 4><<<nb, TB, 0, stream>>>(o2, W3, as3w, ad3w, h3, as3, ad3, N);
  k_edge3<<<nb, TB, 0, stream>>>(rowStart, deg, colIdx, h3, as3, ad3, b3, Wc, bc, out, N);
}

// Round 4
// 493.242 us; speedup vs baseline: 1.2174x; 1.2174x over previous
//
#include <hip/hip_runtime.h>

#define TB 256
#define NGRP 8            // XCDs on MI355X; blockIdx%8 round-robins across XCDs
#define NB_P 1024         // partition blocks
#define SCAN_T 256
#define SCAN_NPT 2
#define SCAN_NPB (SCAN_T * SCAN_NPT)

typedef int      i4v __attribute__((ext_vector_type(4)));
typedef float    f4v __attribute__((ext_vector_type(4)));
typedef _Float16 h4v __attribute__((ext_vector_type(4)));

static __device__ __forceinline__ float leaky(float x) {
  return x > 0.f ? x : 0.2f * x;
}

// ================= CSR build: bucket partition + local fill =================

// A1: per-block bucket counts + per-XCD private histogram (XCD-local atomics).
__global__ void k_bcount(const int* __restrict__ dstA, int* __restrict__ cnt,
                         int* __restrict__ hist, int N, int E4, int E, int R, int CH4) {
  __shared__ int lc[NGRP];
  if (threadIdx.x < NGRP) lc[threadIdx.x] = 0;
  __syncthreads();
  int* histg = hist + (size_t)(blockIdx.x & (NGRP - 1)) * N;
  const int bstart = blockIdx.x * CH4;
  const int bend = min(E4, bstart + CH4);
  const i4v* d4 = reinterpret_cast<const i4v*>(dstA);
  for (int i = bstart + threadIdx.x; i < bend; i += TB) {
    i4v d = __builtin_nontemporal_load(&d4[i]);
#pragma unroll
    for (int k = 0; k < 4; ++k) {
      int dd = d[k];
      int b = dd / R;
      atomicAdd(&lc[b], 1);
      atomicAdd(&histg[dd], 1);
    }
  }
  if (blockIdx.x == NB_P - 1) {  // tail edges
    for (int t = E4 * 4 + threadIdx.x; t < E; t += TB) {
      int dd = dstA[t];
      atomicAdd(&lc[dd / R], 1);
      atomicAdd(&histg[dd], 1);
    }
  }
  __syncthreads();
  if (threadIdx.x < NGRP) cnt[blockIdx.x * NGRP + threadIdx.x] = lc[threadIdx.x];
}

// deg[n] = sum over the 8 private histograms
__global__ void k_hreduce(const int* __restrict__ hist, int* __restrict__ deg, int N) {
  int n = blockIdx.x * blockDim.x + threadIdx.x;
  if (n >= N) return;
  int s = 0;
#pragma unroll
  for (int g = 0; g < NGRP; ++g) s += hist[(size_t)g * N + n];
  deg[n] = s;
}

// A2: column-wise exclusive scan of cnt[NB_P][8] -> off[NB_P][8]; bucketBase[9].
__global__ void k_bscan(const int* __restrict__ cnt, int* __restrict__ off,
                        int* __restrict__ bucketBase) {
  __shared__ int sh[NB_P];
  const int t = threadIdx.x;
  int base = 0;
  for (int g = 0; g < NGRP; ++g) {
    int v = cnt[t * NGRP + g];
    sh[t] = v;
    __syncthreads();
    for (int o = 1; o < NB_P; o <<= 1) {
      int u = (t >= o) ? sh[t - o] : 0;
      __syncthreads();
      sh[t] += u;
      __syncthreads();
    }
    int incl = sh[t];
    off[t * NGRP + g] = base + incl - v;
    if (t == 0) bucketBase[g] = base;
    int total = sh[NB_P - 1];
    __syncthreads();
    base += total;
  }
  if (t == 0) bucketBase[NGRP] = base;
}

// A3: scatter (src,dst) into dst-range buckets using per-block LDS cursors.
__global__ void k_bscatter(const int* __restrict__ srcA, const int* __restrict__ dstA,
                           const int* __restrict__ off, int* __restrict__ es,
                           int* __restrict__ ed, int E4, int E, int R, int CH4) {
  __shared__ int lcur[NGRP];
  if (threadIdx.x < NGRP) lcur[threadIdx.x] = off[blockIdx.x * NGRP + threadIdx.x];
  __syncthreads();
  const int bstart = blockIdx.x * CH4;
  const int bend = min(E4, bstart + CH4);
  const i4v* d4 = reinterpret_cast<const i4v*>(dstA);
  const i4v* s4 = reinterpret_cast<const i4v*>(srcA);
  for (int i = bstart + threadIdx.x; i < bend; i += TB) {
    i4v d = __builtin_nontemporal_load(&d4[i]);
    i4v sv = __builtin_nontemporal_load(&s4[i]);
#pragma unroll
    for (int k = 0; k < 4; ++k) {
      int dd = d[k];
      int pos = atomicAdd(&lcur[dd / R], 1);
      ed[pos] = dd;
      es[pos] = sv[k];
    }
  }
  if (blockIdx.x == NB_P - 1) {
    for (int t = E4 * 4 + threadIdx.x; t < E; t += TB) {
      int dd = dstA[t];
      int pos = atomicAdd(&lcur[dd / R], 1);
      ed[pos] = dd;
      es[pos] = srcA[t];
    }
  }
}

// B: per-XCD local CSR fill from its bucket (sequential read, local scatter).
__global__ void kb_fill(const int* __restrict__ es, const int* __restrict__ ed,
                        const int* __restrict__ bucketBase, int* __restrict__ cursor,
                        int* __restrict__ colIdx) {
  const int g = blockIdx.x & (NGRP - 1);
  const int lb = blockIdx.x / NGRP;
  const int nbg = gridDim.x / NGRP;
  const int lo = bucketBase[g], hi = bucketBase[g + 1];
  for (int i = lo + lb * TB + threadIdx.x; i < hi; i += nbg * TB) {
    int dd = ed[i];
    int ss = es[i];
    int pos = atomicAdd(&cursor[dd], 1);
    colIdx[pos] = ss;
  }
}

// -------- prefix scan of deg -> rowStart (N+1), cursor --------

__global__ void k_scan1(const int* __restrict__ deg, int* __restrict__ part, int N) {
  __shared__ int red[SCAN_T];
  const int t = threadIdx.x;
  const int base = blockIdx.x * SCAN_NPB + t * SCAN_NPT;
  int s = 0;
#pragma unroll
  for (int i = 0; i < SCAN_NPT; ++i) {
    int idx = base + i;
    if (idx < N) s += deg[idx];
  }
  red[t] = s;
  __syncthreads();
  for (int off = SCAN_T / 2; off > 0; off >>= 1) {
    if (t < off) red[t] += red[t + off];
    __syncthreads();
  }
  if (t == 0) part[blockIdx.x] = red[0];
}

__global__ void k_scan2(int* __restrict__ part, int nb) {
  __shared__ int sh[1024];
  const int t = threadIdx.x;
  sh[t] = (t < nb) ? part[t] : 0;
  __syncthreads();
  for (int off = 1; off < 1024; off <<= 1) {
    int v = (t >= off) ? sh[t - off] : 0;
    __syncthreads();
    sh[t] += v;
    __syncthreads();
  }
  if (t < nb) part[t] = (t == 0) ? 0 : sh[t - 1];
}

__global__ void k_scan3(const int* __restrict__ deg, const int* __restrict__ part,
                        int* __restrict__ rowStart, int* __restrict__ cursor, int N) {
  __shared__ int sh[SCAN_T];
  const int t = threadIdx.x;
  const int base = blockIdx.x * SCAN_NPB + t * SCAN_NPT;
  int v[SCAN_NPT];
  int s = 0;
#pragma unroll
  for (int i = 0; i < SCAN_NPT; ++i) {
    int idx = base + i;
    v[i] = (idx < N) ? deg[idx] : 0;
    s += v[i];
  }
  sh[t] = s;
  __syncthreads();
  for (int off = 1; off < SCAN_T; off <<= 1) {
    int u = (t >= off) ? sh[t - off] : 0;
    __syncthreads();
    sh[t] += u;
    __syncthreads();
  }
  int excl = ((t == 0) ? 0 : sh[t - 1]) + part[blockIdx.x];
#pragma unroll
  for (int i = 0; i < SCAN_NPT; ++i) {
    int idx = base + i;
    if (idx < N) {
      rowStart[idx] = excl;
      cursor[idx] = excl;
      excl += v[i];
      if (idx == N - 1) rowStart[N] = excl;
    }
  }
}

// ================= node transform: h = x@W (fp16), alphas (fp32) =================

template <int IN, int H, int C, bool NT>
__global__ void k_node(const float* __restrict__ xin, const float* __restrict__ W,
                       const float* __restrict__ a_src, const float* __restrict__ a_dst,
                       _Float16* __restrict__ hout, float* __restrict__ as_,
                       float* __restrict__ ad_, int N) {
  constexpr int OUT = H * C;
  __shared__ float Ws[IN * OUT];
  __shared__ float As[OUT], Ad[OUT];
  for (int i = threadIdx.x; i < IN * OUT; i += blockDim.x) Ws[i] = W[i];
  if (threadIdx.x < OUT) {
    As[threadIdx.x] = a_src[threadIdx.x];
    Ad[threadIdx.x] = a_dst[threadIdx.x];
  }
  __syncthreads();
  int n = blockIdx.x * blockDim.x + threadIdx.x;
  if (n >= N) return;
  float acc[OUT];
#pragma unroll
  for (int j = 0; j < OUT; ++j) acc[j] = 0.f;
  const f4v* x4 = reinterpret_cast<const f4v*>(xin + (size_t)n * IN);
#pragma unroll
  for (int k4 = 0; k4 < IN / 4; ++k4) {
    f4v xv = NT ? __builtin_nontemporal_load(&x4[k4]) : x4[k4];
#pragma unroll
    for (int j = 0; j < OUT; ++j) {
      acc[j] += xv[0] * Ws[(4 * k4 + 0) * OUT + j];
      acc[j] += xv[1] * Ws[(4 * k4 + 1) * OUT + j];
      acc[j] += xv[2] * Ws[(4 * k4 + 2) * OUT + j];
      acc[j] += xv[3] * Ws[(4 * k4 + 3) * OUT + j];
    }
  }
  h4v* h4 = reinterpret_cast<h4v*>(hout + (size_t)n * OUT);
#pragma unroll
  for (int j4 = 0; j4 < OUT / 4; ++j4) {
    h4v v;
    v[0] = (_Float16)acc[4 * j4 + 0];
    v[1] = (_Float16)acc[4 * j4 + 1];
    v[2] = (_Float16)acc[4 * j4 + 2];
    v[3] = (_Float16)acc[4 * j4 + 3];
    h4[j4] = v;
  }
#pragma unroll
  for (int hh = 0; hh < H; ++hh) {
    float ss = 0.f, dd = 0.f;
#pragma unroll
    for (int c = 0; c < C; ++c) {
      ss += acc[hh * C + c] * As[hh * C + c];
      dd += acc[hh * C + c] * Ad[hh * C + c];
    }
    as_[n * H + hh] = ss;
    ad_[n * H + hh] = dd;
  }
}

// ================= edge aggregation =================
// L feature-lanes x S edge-split sub-lanes per node. Direct exp (logits bounded
// ~13 -> no max pass). Shuffle-combine partials over S. XCD-aligned: group g
// handles nodes [g*R,(g+1)*R) whose colIdx segment was written by XCD g.

template <int H, int C, int L, int S, bool RELU>
__global__ void k_edge_ml(const int* __restrict__ rowStart, const int* __restrict__ colIdx,
                          const _Float16* __restrict__ hfeat, const float* __restrict__ as_,
                          const float* __restrict__ ad_, const float* __restrict__ bias,
                          float* __restrict__ out, int N, int R) {
  constexpr int OUT = H * C;
  static_assert(OUT == L * 4, "lane layout");
  constexpr int LS = L * S;
  constexpr int NPB = TB / LS;
  const int g = blockIdx.x & (NGRP - 1);
  const int lb = blockIdx.x / NGRP;
  const int lane = threadIdx.x % LS;
  const int sub = lane / L;
  const int j = lane % L;
  const int n = g * R + lb * NPB + threadIdx.x / LS;
  const int nEnd = min((g + 1) * R, N);
  if (n >= nEnd) return;
  const int hh = (j * 4) / C;
  const float adv = ad_[n * H + hh];
  const int start = rowStart[n];
  const int cnt = rowStart[n + 1] - start;
  const int lo = start + (cnt * sub) / S;
  const int hi = start + (cnt * (sub + 1)) / S;
  float s = 0.f, acc0 = 0.f, acc1 = 0.f, acc2 = 0.f, acc3 = 0.f;
  if (sub == 0) {  // self-loop
    float p = __expf(leaky(as_[n * H + hh] + adv));
    h4v a0 = reinterpret_cast<const h4v*>(hfeat + (size_t)n * OUT)[j];
    s = p;
    acc0 = p * (float)a0[0];
    acc1 = p * (float)a0[1];
    acc2 = p * (float)a0[2];
    acc3 = p * (float)a0[3];
  }
  for (int i = lo; i < hi; ++i) {
    int src = colIdx[i];
    h4v hv = reinterpret_cast<const h4v*>(hfeat + (size_t)src * OUT)[j];
    float p = __expf(leaky(as_[src * H + hh] + adv));
    s += p;
    acc0 += p * (float)hv[0];
    acc1 += p * (float)hv[1];
    acc2 += p * (float)hv[2];
    acc3 += p * (float)hv[3];
  }
#pragma unroll
  for (int off = L; off < LS; off <<= 1) {
    s += __shfl_xor(s, off);
    acc0 += __shfl_xor(acc0, off);
    acc1 += __shfl_xor(acc1, off);
    acc2 += __shfl_xor(acc2, off);
    acc3 += __shfl_xor(acc3, off);
  }
  if (sub == 0) {
    float inv = 1.f / (s + 1e-16f);
    float4 bb = reinterpret_cast<const float4*>(bias)[j];
    float4 o;
    o.x = acc0 * inv + bb.x;
    o.y = acc1 * inv + bb.y;
    o.z = acc2 * inv + bb.z;
    o.w = acc3 * inv + bb.w;
    if (RELU) {
      o.x = fmaxf(o.x, 0.f);
      o.y = fmaxf(o.y, 0.f);
      o.z = fmaxf(o.z, 0.f);
      o.w = fmaxf(o.w, 0.f);
    }
    reinterpret_cast<float4*>(out + (size_t)n * OUT)[j] = o;
  }
}

// layer-3 (H=1,C=4) edge aggregation + fused classifier; S=4 edge-split
__global__ void k_edge3(const int* __restrict__ rowStart, const int* __restrict__ colIdx,
                        const _Float16* __restrict__ hfeat, const float* __restrict__ as_,
                        const float* __restrict__ ad_, const float* __restrict__ b3,
                        const float* __restrict__ Wc, const float* __restrict__ bc,
                        float* __restrict__ out, int N, int R) {
  constexpr int S = 4;
  constexpr int NPB = TB / S;
  const int g = blockIdx.x & (NGRP - 1);
  const int lb = blockIdx.x / NGRP;
  const int sub = threadIdx.x % S;
  const int n = g * R + lb * NPB + threadIdx.x / S;
  const int nEnd = min((g + 1) * R, N);
  if (n >= nEnd) return;
  const float adv = ad_[n];
  const int start = rowStart[n];
  const int cnt = rowStart[n + 1] - start;
  const int lo = start + (cnt * sub) / S;
  const int hi = start + (cnt * (sub + 1)) / S;
  float s = 0.f, acc0 = 0.f, acc1 = 0.f, acc2 = 0.f, acc3 = 0.f;
  if (sub == 0) {
    float p = __expf(leaky(as_[n] + adv));
    h4v a0 = reinterpret_cast<const h4v*>(hfeat)[n];
    s = p;
    acc0 = p * (float)a0[0];
    acc1 = p * (float)a0[1];
    acc2 = p * (float)a0[2];
    acc3 = p * (float)a0[3];
  }
  for (int i = lo; i < hi; ++i) {
    int src = colIdx[i];
    h4v hv = reinterpret_cast<const h4v*>(hfeat)[src];
    float p = __expf(leaky(as_[src] + adv));
    s += p;
    acc0 += p * (float)hv[0];
    acc1 += p * (float)hv[1];
    acc2 += p * (float)hv[2];
    acc3 += p * (float)hv[3];
  }
#pragma unroll
  for (int off = 1; off < S; off <<= 1) {
    s += __shfl_xor(s, off);
    acc0 += __shfl_xor(acc0, off);
    acc1 += __shfl_xor(acc1, off);
    acc2 += __shfl_xor(acc2, off);
    acc3 += __shfl_xor(acc3, off);
  }
  if (sub == 0) {
    float inv = 1.f / (s + 1e-16f);
    float o0 = acc0 * inv + b3[0];
    float o1 = acc1 * inv + b3[1];
    float o2 = acc2 * inv + b3[2];
    float o3 = acc3 * inv + b3[3];
    float2 r;
    r.x = o0 * Wc[0] + o1 * Wc[2] + o2 * Wc[4] + o3 * Wc[6] + bc[0];
    r.y = o0 * Wc[1] + o1 * Wc[3] + o2 * Wc[5] + o3 * Wc[7] + bc[1];
    reinterpret_cast<float2*>(out)[n] = r;
  }
}

// ================= launch =================

extern "C" void kernel_launch(void* const* d_in, const int* in_sizes, int n_in,
                              void* d_out, int out_size, void* d_ws, size_t ws_size,
                              hipStream_t stream) {
  const float* x    = (const float*)d_in[0];
  const int*   ei   = (const int*)d_in[1];
  const float* W1   = (const float*)d_in[2];
  const float* as1w = (const float*)d_in[3];
  const float* ad1w = (const float*)d_in[4];
  const float* b1   = (const float*)d_in[5];
  const float* W2   = (const float*)d_in[6];
  const float* as2w = (const float*)d_in[7];
  const float* ad2w = (const float*)d_in[8];
  const float* b2   = (const float*)d_in[9];
  const float* W3   = (const float*)d_in[10];
  const float* as3w = (const float*)d_in[11];
  const float* ad3w = (const float*)d_in[12];
  const float* b3   = (const float*)d_in[13];
  const float* Wc   = (const float*)d_in[14];
  const float* bc   = (const float*)d_in[15];
  float* out = (float*)d_out;

  const int N = in_sizes[0] / 128;
  const int E = in_sizes[1] / 2;
  const int* srcA = ei;
  const int* dstA = ei + E;

  char* p = (char*)d_ws;
  auto alloc = [&](size_t bytes) -> void* {
    void* r = (void*)p;
    p += (bytes + 255) & ~(size_t)255;
    return r;
  };
  int* hist     = (int*)alloc((size_t)NGRP * N * 4);
  int* cnt      = (int*)alloc((size_t)NB_P * NGRP * 4);
  int* off      = (int*)alloc((size_t)NB_P * NGRP * 4);
  int* bucketBase = (int*)alloc((NGRP + 1) * 4);
  int* deg      = (int*)alloc((size_t)N * 4);
  int* rowStart = (int*)alloc((size_t)(N + 1) * 4);
  int* cursor   = (int*)alloc((size_t)N * 4);
  int* part     = (int*)alloc(1024 * 4);
  int* colIdx   = (int*)alloc((size_t)E * 4);
  int* es       = (int*)alloc((size_t)E * 4);
  int* ed       = (int*)alloc((size_t)E * 4);
  _Float16* h1 = (_Float16*)alloc((size_t)N * 16 * 2);
  float* as1 = (float*)alloc((size_t)N * 2 * 4);
  float* ad1 = (float*)alloc((size_t)N * 2 * 4);
  float* o1  = (float*)alloc((size_t)N * 16 * 4);
  _Float16* h2 = (_Float16*)alloc((size_t)N * 8 * 2);
  float* as2 = (float*)alloc((size_t)N * 2 * 4);
  float* ad2 = (float*)alloc((size_t)N * 2 * 4);
  float* o2  = (float*)alloc((size_t)N * 8 * 4);
  _Float16* h3 = (_Float16*)alloc((size_t)N * 4 * 2);
  float* as3 = (float*)alloc((size_t)N * 4);
  float* ad3 = (float*)alloc((size_t)N * 4);

  const int R   = (N + NGRP - 1) / NGRP;
  const int E4  = E >> 2;
  const int CH4 = (E4 + NB_P - 1) / NB_P;
  const int nb  = (N + TB - 1) / TB;
  const int sb  = (N + SCAN_NPB - 1) / SCAN_NPB;

  hipMemsetAsync(hist, 0, (size_t)NGRP * N * 4, stream);

  // CSR build
  k_bcount<<<NB_P, TB, 0, stream>>>(dstA, cnt, hist, N, E4, E, R, CH4);
  k_hreduce<<<nb, TB, 0, stream>>>(hist, deg, N);
  k_bscan<<<1, NB_P, 0, stream>>>(cnt, off, bucketBase);
  k_scan1<<<sb, SCAN_T, 0, stream>>>(deg, part, N);
  k_scan2<<<1, 1024, 0, stream>>>(part, sb);
  k_scan3<<<sb, SCAN_T, 0, stream>>>(deg, part, rowStart, cursor, N);
  k_bscatter<<<NB_P, TB, 0, stream>>>(srcA, dstA, off, es, ed, E4, E, R, CH4);
  kb_fill<<<1024, TB, 0, stream>>>(es, ed, bucketBase, cursor, colIdx);

  // edge-kernel grids: NGRP * ceil(R / nodes-per-block)
  const int g1 = NGRP * ((R + (TB / 8) - 1) / (TB / 8));   // L=4,S=2
  const int g2 = NGRP * ((R + (TB / 4) - 1) / (TB / 4));   // L=2,S=2
  const int g3 = NGRP * ((R + (TB / 4) - 1) / (TB / 4));   // S=4

  // layer 1: in=128, H=2, C=8
  k_node<128, 2, 8, true><<<nb, TB, 0, stream>>>(x, W1, as1w, ad1w, h1, as1, ad1, N);
  k_edge_ml<2, 8, 4, 2, true><<<g1, TB, 0, stream>>>(rowStart, colIdx, h1, as1, ad1, b1, o1, N, R);

  // layer 2: in=16, H=2, C=4
  k_node<16, 2, 4, false><<<nb, TB, 0, stream>>>(o1, W2, as2w, ad2w, h2, as2, ad2, N);
  k_edge_ml<2, 4, 2, 2, true><<<g2, TB, 0, stream>>>(rowStart, colIdx, h2, as2, ad2, b2, o2, N, R);

  // layer 3: in=8, H=1, C=4 + fused classifier
  k_node<8, 1, 4, false><<<nb, TB, 0, stream>>>(o2, W3, as3w, ad3w, h3, as3, ad3, N);
  k_edge3<<<g3, TB, 0, stream>>>(rowStart, colIdx, h3, as3, ad3, b3, Wc, bc, out, N, R);
}

// Round 5
// 249.444 us; speedup vs baseline: 2.4072x; 1.9774x over previous
//
#include <hip/hip_runtime.h>

#define TB 256
#define NGRP 8            // XCDs on MI355X; blockIdx%8 round-robins across XCDs
#define NB_P 256          // partition blocks
#define TBP 256           // partition block threads
#define NBKT 256          // dst-range buckets (32 per XCD)
#define SORT_T 1024

typedef int      i4v __attribute__((ext_vector_type(4)));
typedef float    f4v __attribute__((ext_vector_type(4)));
typedef _Float16 h4v __attribute__((ext_vector_type(4)));

static __device__ __forceinline__ float leaky(float x) {
  return x > 0.f ? x : 0.2f * x;
}

// ================= CSR build: 256-bucket partition + per-bucket LDS sort =================

// A1: per-block bucket counts (LDS), cnt laid out [bucket][block] for coalesced scan.
__global__ void k_bcount(const int* __restrict__ dstA, int* __restrict__ cnt,
                         int E4, int E, unsigned M, int CH4) {
  __shared__ int lc[NBKT];
  for (int i = threadIdx.x; i < NBKT; i += TBP) lc[i] = 0;
  __syncthreads();
  const int bstart = blockIdx.x * CH4;
  const int bend = min(E4, bstart + CH4);
  const i4v* d4 = reinterpret_cast<const i4v*>(dstA);
  for (int i = bstart + threadIdx.x; i < bend; i += TBP) {
    i4v d = __builtin_nontemporal_load(&d4[i]);
#pragma unroll
    for (int k = 0; k < 4; ++k) atomicAdd(&lc[__umulhi((unsigned)d[k], M)], 1);
  }
  if (blockIdx.x == NB_P - 1) {
    for (int t = E4 * 4 + threadIdx.x; t < E; t += TBP)
      atomicAdd(&lc[__umulhi((unsigned)dstA[t], M)], 1);
  }
  __syncthreads();
  for (int b = threadIdx.x; b < NBKT; b += TBP) cnt[b * NB_P + blockIdx.x] = lc[b];
}

// A2a: per-bucket exclusive scan over blocks (grid = NBKT, block = NB_P threads).
__global__ void k_bscan1(const int* __restrict__ cnt, int* __restrict__ off,
                         int* __restrict__ colTotal) {
  __shared__ int sh[NB_P];
  const int t = threadIdx.x;
  const int b = blockIdx.x;
  int v = cnt[b * NB_P + t];
  sh[t] = v;
  __syncthreads();
  for (int o = 1; o < NB_P; o <<= 1) {
    int u = (t >= o) ? sh[t - o] : 0;
    __syncthreads();
    sh[t] += u;
    __syncthreads();
  }
  off[b * NB_P + t] = sh[t] - v;
  if (t == NB_P - 1) colTotal[b] = sh[t];
}

// A2b: exclusive scan of bucket totals -> bucketBase[NBKT+1].
__global__ void k_bscan2(const int* __restrict__ colTotal, int* __restrict__ bucketBase) {
  __shared__ int sh[NBKT];
  const int t = threadIdx.x;
  int v = colTotal[t];
  sh[t] = v;
  __syncthreads();
  for (int o = 1; o < NBKT; o <<= 1) {
    int u = (t >= o) ? sh[t - o] : 0;
    __syncthreads();
    sh[t] += u;
    __syncthreads();
  }
  bucketBase[t] = sh[t] - v;
  if (t == NBKT - 1) bucketBase[NBKT] = sh[t];
}

// A3: scatter packed (dloc<<17 | src) into bucket segments via LDS cursors.
__global__ void k_bscatter(const int* __restrict__ srcA, const int* __restrict__ dstA,
                           const int* __restrict__ off, const int* __restrict__ bucketBase,
                           int* __restrict__ epk, int E4, int E, unsigned M, int R, int CH4) {
  __shared__ int lcur[NBKT];
  for (int i = threadIdx.x; i < NBKT; i += TBP)
    lcur[i] = bucketBase[i] + off[i * NB_P + blockIdx.x];
  __syncthreads();
  const int bstart = blockIdx.x * CH4;
  const int bend = min(E4, bstart + CH4);
  const i4v* d4 = reinterpret_cast<const i4v*>(dstA);
  const i4v* s4 = reinterpret_cast<const i4v*>(srcA);
  for (int i = bstart + threadIdx.x; i < bend; i += TBP) {
    i4v d = __builtin_nontemporal_load(&d4[i]);
    i4v sv = __builtin_nontemporal_load(&s4[i]);
#pragma unroll
    for (int k = 0; k < 4; ++k) {
      int dd = d[k];
      int b = __umulhi((unsigned)dd, M);
      int pos = atomicAdd(&lcur[b], 1);
      epk[pos] = ((dd - b * R) << 17) | sv[k];
    }
  }
  if (blockIdx.x == NB_P - 1) {
    for (int t = E4 * 4 + threadIdx.x; t < E; t += TBP) {
      int dd = dstA[t];
      int b = __umulhi((unsigned)dd, M);
      int pos = atomicAdd(&lcur[b], 1);
      epk[pos] = ((dd - b * R) << 17) | srcA[t];
    }
  }
}

// B: per-bucket counting sort in LDS -> rowStart slice + colIdx segment.
// Bucket b mapped so XCD g = b/32 processes its own node range.
__global__ void k_bsort(const int* __restrict__ epk, const int* __restrict__ bucketBase,
                        int* __restrict__ rowStart, int* __restrict__ colIdx,
                        int N, int R, int E) {
  __shared__ int sc[512];
  const int b = (blockIdx.x & (NGRP - 1)) * (NBKT / NGRP) + (blockIdx.x >> 3);
  const int lo = bucketBase[b], hi = bucketBase[b + 1];
  const int nodeLo = b * R;
  const int nN = min(R, N - nodeLo);
  const int t = threadIdx.x;
  if (t < 512) sc[t] = 0;
  __syncthreads();
  for (int i = lo + t; i < hi; i += SORT_T) {
    int pk = __builtin_nontemporal_load(&epk[i]);
    atomicAdd(&sc[pk >> 17], 1);
  }
  __syncthreads();
  int own = (t < 512) ? sc[t] : 0;
  for (int o = 1; o < 512; o <<= 1) {
    int u = (t < 512 && t >= o) ? sc[t - o] : 0;
    __syncthreads();
    if (t < 512) sc[t] += u;
    __syncthreads();
  }
  if (t < nN) rowStart[nodeLo + t] = lo + sc[t] - own;
  if (b == NBKT - 1 && t == 0) rowStart[N] = E;
  if (t < 512) sc[t] -= own;  // exclusive offsets become LDS cursors
  __syncthreads();
  for (int i = lo + t; i < hi; i += SORT_T) {
    int pk = __builtin_nontemporal_load(&epk[i]);
    int pos = lo + atomicAdd(&sc[pk >> 17], 1);
    colIdx[pos] = pk & 0x1FFFF;
  }
}

// ================= node transform: h = x@W (fp16), alphas (fp32) =================

template <int IN, int H, int C, bool NT>
__global__ void k_node(const float* __restrict__ xin, const float* __restrict__ W,
                       const float* __restrict__ a_src, const float* __restrict__ a_dst,
                       _Float16* __restrict__ hout, float* __restrict__ as_,
                       float* __restrict__ ad_, int N) {
  constexpr int OUT = H * C;
  __shared__ float Ws[IN * OUT];
  __shared__ float As[OUT], Ad[OUT];
  for (int i = threadIdx.x; i < IN * OUT; i += blockDim.x) Ws[i] = W[i];
  if (threadIdx.x < OUT) {
    As[threadIdx.x] = a_src[threadIdx.x];
    Ad[threadIdx.x] = a_dst[threadIdx.x];
  }
  __syncthreads();
  int n = blockIdx.x * blockDim.x + threadIdx.x;
  if (n >= N) return;
  float acc[OUT];
#pragma unroll
  for (int j = 0; j < OUT; ++j) acc[j] = 0.f;
  const f4v* x4 = reinterpret_cast<const f4v*>(xin + (size_t)n * IN);
#pragma unroll
  for (int k4 = 0; k4 < IN / 4; ++k4) {
    f4v xv = NT ? __builtin_nontemporal_load(&x4[k4]) : x4[k4];
#pragma unroll
    for (int j = 0; j < OUT; ++j) {
      acc[j] += xv[0] * Ws[(4 * k4 + 0) * OUT + j];
      acc[j] += xv[1] * Ws[(4 * k4 + 1) * OUT + j];
      acc[j] += xv[2] * Ws[(4 * k4 + 2) * OUT + j];
      acc[j] += xv[3] * Ws[(4 * k4 + 3) * OUT + j];
    }
  }
  h4v* h4 = reinterpret_cast<h4v*>(hout + (size_t)n * OUT);
#pragma unroll
  for (int j4 = 0; j4 < OUT / 4; ++j4) {
    h4v v;
    v[0] = (_Float16)acc[4 * j4 + 0];
    v[1] = (_Float16)acc[4 * j4 + 1];
    v[2] = (_Float16)acc[4 * j4 + 2];
    v[3] = (_Float16)acc[4 * j4 + 3];
    h4[j4] = v;
  }
#pragma unroll
  for (int hh = 0; hh < H; ++hh) {
    float ss = 0.f, dd = 0.f;
#pragma unroll
    for (int c = 0; c < C; ++c) {
      ss += acc[hh * C + c] * As[hh * C + c];
      dd += acc[hh * C + c] * Ad[hh * C + c];
    }
    as_[n * H + hh] = ss;
    ad_[n * H + hh] = dd;
  }
}

// ================= edge aggregation =================
// L feature-lanes x S edge-split sub-lanes per node; direct exp; shuffle combine.
// XCD-aligned: group g handles nodes [g*R8,(g+1)*R8) whose colIdx lives on XCD g.

template <int H, int C, int L, int S, bool RELU>
__global__ void k_edge_ml(const int* __restrict__ rowStart, const int* __restrict__ colIdx,
                          const _Float16* __restrict__ hfeat, const float* __restrict__ as_,
                          const float* __restrict__ ad_, const float* __restrict__ bias,
                          float* __restrict__ out, int N, int R8) {
  constexpr int OUT = H * C;
  static_assert(OUT == L * 4, "lane layout");
  constexpr int LS = L * S;
  constexpr int NPB = TB / LS;
  const int g = blockIdx.x & (NGRP - 1);
  const int lb = blockIdx.x / NGRP;
  const int lane = threadIdx.x % LS;
  const int sub = lane / L;
  const int j = lane % L;
  const int n = g * R8 + lb * NPB + threadIdx.x / LS;
  const int nEnd = min((g + 1) * R8, N);
  if (n >= nEnd) return;
  const int hh = (j * 4) / C;
  const float adv = ad_[n * H + hh];
  const int start = rowStart[n];
  const int cnt = rowStart[n + 1] - start;
  const int lo = start + (cnt * sub) / S;
  const int hi = start + (cnt * (sub + 1)) / S;
  float s = 0.f, acc0 = 0.f, acc1 = 0.f, acc2 = 0.f, acc3 = 0.f;
  if (sub == 0) {  // self-loop
    float p = __expf(leaky(as_[n * H + hh] + adv));
    h4v a0 = reinterpret_cast<const h4v*>(hfeat + (size_t)n * OUT)[j];
    s = p;
    acc0 = p * (float)a0[0];
    acc1 = p * (float)a0[1];
    acc2 = p * (float)a0[2];
    acc3 = p * (float)a0[3];
  }
  for (int i = lo; i < hi; ++i) {
    int src = colIdx[i];
    h4v hv = reinterpret_cast<const h4v*>(hfeat + (size_t)src * OUT)[j];
    float p = __expf(leaky(as_[src * H + hh] + adv));
    s += p;
    acc0 += p * (float)hv[0];
    acc1 += p * (float)hv[1];
    acc2 += p * (float)hv[2];
    acc3 += p * (float)hv[3];
  }
#pragma unroll
  for (int off = L; off < LS; off <<= 1) {
    s += __shfl_xor(s, off);
    acc0 += __shfl_xor(acc0, off);
    acc1 += __shfl_xor(acc1, off);
    acc2 += __shfl_xor(acc2, off);
    acc3 += __shfl_xor(acc3, off);
  }
  if (sub == 0) {
    float inv = 1.f / (s + 1e-16f);
    float4 bb = reinterpret_cast<const float4*>(bias)[j];
    float4 o;
    o.x = acc0 * inv + bb.x;
    o.y = acc1 * inv + bb.y;
    o.z = acc2 * inv + bb.z;
    o.w = acc3 * inv + bb.w;
    if (RELU) {
      o.x = fmaxf(o.x, 0.f);
      o.y = fmaxf(o.y, 0.f);
      o.z = fmaxf(o.z, 0.f);
      o.w = fmaxf(o.w, 0.f);
    }
    reinterpret_cast<float4*>(out + (size_t)n * OUT)[j] = o;
  }
}

// layer-3 (H=1,C=4) edge aggregation + fused classifier; S=4 edge-split
__global__ void k_edge3(const int* __restrict__ rowStart, const int* __restrict__ colIdx,
                        const _Float16* __restrict__ hfeat, const float* __restrict__ as_,
                        const float* __restrict__ ad_, const float* __restrict__ b3,
                        const float* __restrict__ Wc, const float* __restrict__ bc,
                        float* __restrict__ out, int N, int R8) {
  constexpr int S = 4;
  constexpr int NPB = TB / S;
  const int g = blockIdx.x & (NGRP - 1);
  const int lb = blockIdx.x / NGRP;
  const int sub = threadIdx.x % S;
  const int n = g * R8 + lb * NPB + threadIdx.x / S;
  const int nEnd = min((g + 1) * R8, N);
  if (n >= nEnd) return;
  const float adv = ad_[n];
  const int start = rowStart[n];
  const int cnt = rowStart[n + 1] - start;
  const int lo = start + (cnt * sub) / S;
  const int hi = start + (cnt * (sub + 1)) / S;
  float s = 0.f, acc0 = 0.f, acc1 = 0.f, acc2 = 0.f, acc3 = 0.f;
  if (sub == 0) {
    float p = __expf(leaky(as_[n] + adv));
    h4v a0 = reinterpret_cast<const h4v*>(hfeat)[n];
    s = p;
    acc0 = p * (float)a0[0];
    acc1 = p * (float)a0[1];
    acc2 = p * (float)a0[2];
    acc3 = p * (float)a0[3];
  }
  for (int i = lo; i < hi; ++i) {
    int src = colIdx[i];
    h4v hv = reinterpret_cast<const h4v*>(hfeat)[src];
    float p = __expf(leaky(as_[src] + adv));
    s += p;
    acc0 += p * (float)hv[0];
    acc1 += p * (float)hv[1];
    acc2 += p * (float)hv[2];
    acc3 += p * (float)hv[3];
  }
#pragma unroll
  for (int off = 1; off < S; off <<= 1) {
    s += __shfl_xor(s, off);
    acc0 += __shfl_xor(acc0, off);
    acc1 += __shfl_xor(acc1, off);
    acc2 += __shfl_xor(acc2, off);
    acc3 += __shfl_xor(acc3, off);
  }
  if (sub == 0) {
    float inv = 1.f / (s + 1e-16f);
    float o0 = acc0 * inv + b3[0];
    float o1 = acc1 * inv + b3[1];
    float o2 = acc2 * inv + b3[2];
    float o3 = acc3 * inv + b3[3];
    float2 r;
    r.x = o0 * Wc[0] + o1 * Wc[2] + o2 * Wc[4] + o3 * Wc[6] + bc[0];
    r.y = o0 * Wc[1] + o1 * Wc[3] + o2 * Wc[5] + o3 * Wc[7] + bc[1];
    reinterpret_cast<float2*>(out)[n] = r;
  }
}

// ================= launch =================

extern "C" void kernel_launch(void* const* d_in, const int* in_sizes, int n_in,
                              void* d_out, int out_size, void* d_ws, size_t ws_size,
                              hipStream_t stream) {
  const float* x    = (const float*)d_in[0];
  const int*   ei   = (const int*)d_in[1];
  const float* W1   = (const float*)d_in[2];
  const float* as1w = (const float*)d_in[3];
  const float* ad1w = (const float*)d_in[4];
  const float* b1   = (const float*)d_in[5];
  const float* W2   = (const float*)d_in[6];
  const float* as2w = (const float*)d_in[7];
  const float* ad2w = (const float*)d_in[8];
  const float* b2   = (const float*)d_in[9];
  const float* W3   = (const float*)d_in[10];
  const float* as3w = (const float*)d_in[11];
  const float* ad3w = (const float*)d_in[12];
  const float* b3   = (const float*)d_in[13];
  const float* Wc   = (const float*)d_in[14];
  const float* bc   = (const float*)d_in[15];
  float* out = (float*)d_out;

  const int N = in_sizes[0] / 128;
  const int E = in_sizes[1] / 2;
  const int* srcA = ei;
  const int* dstA = ei + E;

  char* p = (char*)d_ws;
  auto alloc = [&](size_t bytes) -> void* {
    void* r = (void*)p;
    p += (bytes + 255) & ~(size_t)255;
    return r;
  };
  int* cnt        = (int*)alloc((size_t)NBKT * NB_P * 4);
  int* off        = (int*)alloc((size_t)NBKT * NB_P * 4);
  int* colTotal   = (int*)alloc(NBKT * 4);
  int* bucketBase = (int*)alloc((NBKT + 1) * 4);
  int* rowStart   = (int*)alloc((size_t)(N + 1) * 4);
  int* epk        = (int*)alloc((size_t)E * 4);
  int* colIdx     = (int*)alloc((size_t)E * 4);
  _Float16* h1 = (_Float16*)alloc((size_t)N * 16 * 2);
  float* as1 = (float*)alloc((size_t)N * 2 * 4);
  float* ad1 = (float*)alloc((size_t)N * 2 * 4);
  float* o1  = (float*)alloc((size_t)N * 16 * 4);
  _Float16* h2 = (_Float16*)alloc((size_t)N * 8 * 2);
  float* as2 = (float*)alloc((size_t)N * 2 * 4);
  float* ad2 = (float*)alloc((size_t)N * 2 * 4);
  float* o2  = (float*)alloc((size_t)N * 8 * 4);
  _Float16* h3 = (_Float16*)alloc((size_t)N * 4 * 2);
  float* as3 = (float*)alloc((size_t)N * 4);
  float* ad3 = (float*)alloc((size_t)N * 4);

  const int R   = (N + NBKT - 1) / NBKT;                       // nodes per bucket (391)
  const unsigned M = (unsigned)(((1ULL << 32) + R - 1) / R);   // exact /R via __umulhi
  const int R8  = R * (NBKT / NGRP);                           // nodes per XCD (12512)
  const int E4  = E >> 2;
  const int CH4 = (E4 + NB_P - 1) / NB_P;
  const int nb  = (N + TB - 1) / TB;

  // CSR build (no global atomics)
  k_bcount<<<NB_P, TBP, 0, stream>>>(dstA, cnt, E4, E, M, CH4);
  k_bscan1<<<NBKT, NB_P, 0, stream>>>(cnt, off, colTotal);
  k_bscan2<<<1, NBKT, 0, stream>>>(colTotal, bucketBase);
  k_bscatter<<<NB_P, TBP, 0, stream>>>(srcA, dstA, off, bucketBase, epk, E4, E, M, R, CH4);
  k_bsort<<<NBKT, SORT_T, 0, stream>>>(epk, bucketBase, rowStart, colIdx, N, R, E);

  // edge-kernel grids: NGRP * ceil(R8 / nodes-per-block)
  const int g1 = NGRP * ((R8 + (TB / 8) - 1) / (TB / 8));   // L=4,S=2
  const int g2 = NGRP * ((R8 + (TB / 4) - 1) / (TB / 4));   // L=2,S=2
  const int g3 = NGRP * ((R8 + (TB / 4) - 1) / (TB / 4));   // S=4

  // layer 1: in=128, H=2, C=8
  k_node<128, 2, 8, true><<<nb, TB, 0, stream>>>(x, W1, as1w, ad1w, h1, as1, ad1, N);
  k_edge_ml<2, 8, 4, 2, true><<<g1, TB, 0, stream>>>(rowStart, colIdx, h1, as1, ad1, b1, o1, N, R8);

  // layer 2: in=16, H=2, C=4
  k_node<16, 2, 4, false><<<nb, TB, 0, stream>>>(o1, W2, as2w, ad2w, h2, as2, ad2, N);
  k_edge_ml<2, 4, 2, 2, true><<<g2, TB, 0, stream>>>(rowStart, colIdx, h2, as2, ad2, b2, o2, N, R8);

  // layer 3: in=8, H=1, C=4 + fused classifier
  k_node<8, 1, 4, false><<<nb, TB, 0, stream>>>(o2, W3, as3w, ad3w, h3, as3, ad3, N);
  k_edge3<<<g3, TB, 0, stream>>>(rowStart, colIdx, h3, as3, ad3, b3, Wc, bc, out, N, R8);
}

// Round 6
// 229.231 us; speedup vs baseline: 2.6195x; 1.0882x over previous
//
#include <hip/hip_runtime.h>

#define TB 256
#define NGRP 8            // XCDs on MI355X; blockIdx%8 round-robins across XCDs
#define NB_P 256          // partition blocks
#define TBP 256           // partition block threads
#define NBKT 256          // dst-range buckets (32 per XCD)
#define SORT_T 1024

typedef int      i4v __attribute__((ext_vector_type(4)));
typedef float    f4v __attribute__((ext_vector_type(4)));
typedef _Float16 h4v __attribute__((ext_vector_type(4)));

static __device__ __forceinline__ float leaky(float x) {
  return x > 0.f ? x : 0.2f * x;
}

// ================= CSR build: 256-bucket partition + per-bucket LDS sort =================

// A1: per-block bucket counts (LDS), cnt laid out [bucket][block] for coalesced scan.
__global__ void k_bcount(const int* __restrict__ dstA, int* __restrict__ cnt,
                         int E4, int E, unsigned M, int CH4) {
  __shared__ int lc[NBKT];
  for (int i = threadIdx.x; i < NBKT; i += TBP) lc[i] = 0;
  __syncthreads();
  const int bstart = blockIdx.x * CH4;
  const int bend = min(E4, bstart + CH4);
  const i4v* d4 = reinterpret_cast<const i4v*>(dstA);
  for (int i = bstart + threadIdx.x; i < bend; i += TBP) {
    i4v d = __builtin_nontemporal_load(&d4[i]);
#pragma unroll
    for (int k = 0; k < 4; ++k) atomicAdd(&lc[__umulhi((unsigned)d[k], M)], 1);
  }
  if (blockIdx.x == NB_P - 1) {
    for (int t = E4 * 4 + threadIdx.x; t < E; t += TBP)
      atomicAdd(&lc[__umulhi((unsigned)dstA[t], M)], 1);
  }
  __syncthreads();
  for (int b = threadIdx.x; b < NBKT; b += TBP) cnt[b * NB_P + blockIdx.x] = lc[b];
}

// A2a: per-bucket exclusive scan over blocks (grid = NBKT, block = NB_P threads).
__global__ void k_bscan1(const int* __restrict__ cnt, int* __restrict__ off,
                         int* __restrict__ colTotal) {
  __shared__ int sh[NB_P];
  const int t = threadIdx.x;
  const int b = blockIdx.x;
  int v = cnt[b * NB_P + t];
  sh[t] = v;
  __syncthreads();
  for (int o = 1; o < NB_P; o <<= 1) {
    int u = (t >= o) ? sh[t - o] : 0;
    __syncthreads();
    sh[t] += u;
    __syncthreads();
  }
  off[b * NB_P + t] = sh[t] - v;
  if (t == NB_P - 1) colTotal[b] = sh[t];
}

// A2b: exclusive scan of bucket totals -> bucketBase[NBKT+1].
__global__ void k_bscan2(const int* __restrict__ colTotal, int* __restrict__ bucketBase) {
  __shared__ int sh[NBKT];
  const int t = threadIdx.x;
  int v = colTotal[t];
  sh[t] = v;
  __syncthreads();
  for (int o = 1; o < NBKT; o <<= 1) {
    int u = (t >= o) ? sh[t - o] : 0;
    __syncthreads();
    sh[t] += u;
    __syncthreads();
  }
  bucketBase[t] = sh[t] - v;
  if (t == NBKT - 1) bucketBase[NBKT] = sh[t];
}

// A3: scatter packed (dloc<<17 | src) into bucket segments via LDS cursors.
__global__ void k_bscatter(const int* __restrict__ srcA, const int* __restrict__ dstA,
                           const int* __restrict__ off, const int* __restrict__ bucketBase,
                           int* __restrict__ epk, int E4, int E, unsigned M, int R, int CH4) {
  __shared__ int lcur[NBKT];
  for (int i = threadIdx.x; i < NBKT; i += TBP)
    lcur[i] = bucketBase[i] + off[i * NB_P + blockIdx.x];
  __syncthreads();
  const int bstart = blockIdx.x * CH4;
  const int bend = min(E4, bstart + CH4);
  const i4v* d4 = reinterpret_cast<const i4v*>(dstA);
  const i4v* s4 = reinterpret_cast<const i4v*>(srcA);
  for (int i = bstart + threadIdx.x; i < bend; i += TBP) {
    i4v d = __builtin_nontemporal_load(&d4[i]);
    i4v sv = __builtin_nontemporal_load(&s4[i]);
#pragma unroll
    for (int k = 0; k < 4; ++k) {
      int dd = d[k];
      int b = __umulhi((unsigned)dd, M);
      int pos = atomicAdd(&lcur[b], 1);
      epk[pos] = ((dd - b * R) << 17) | sv[k];
    }
  }
  if (blockIdx.x == NB_P - 1) {
    for (int t = E4 * 4 + threadIdx.x; t < E; t += TBP) {
      int dd = dstA[t];
      int b = __umulhi((unsigned)dd, M);
      int pos = atomicAdd(&lcur[b], 1);
      epk[pos] = ((dd - b * R) << 17) | srcA[t];
    }
  }
}

// B: per-bucket counting sort in LDS -> rowStart slice + colIdx segment.
// Bucket b mapped so XCD g = b/32 processes its own node range.
__global__ void k_bsort(const int* __restrict__ epk, const int* __restrict__ bucketBase,
                        int* __restrict__ rowStart, int* __restrict__ colIdx,
                        int N, int R, int E) {
  __shared__ int sc[512];
  const int b = (blockIdx.x & (NGRP - 1)) * (NBKT / NGRP) + (blockIdx.x >> 3);
  const int lo = bucketBase[b], hi = bucketBase[b + 1];
  const int nodeLo = b * R;
  const int nN = min(R, N - nodeLo);
  const int t = threadIdx.x;
  if (t < 512) sc[t] = 0;
  __syncthreads();
  for (int i = lo + t; i < hi; i += SORT_T) {
    int pk = __builtin_nontemporal_load(&epk[i]);
    atomicAdd(&sc[pk >> 17], 1);
  }
  __syncthreads();
  int own = (t < 512) ? sc[t] : 0;
  for (int o = 1; o < 512; o <<= 1) {
    int u = (t < 512 && t >= o) ? sc[t - o] : 0;
    __syncthreads();
    if (t < 512) sc[t] += u;
    __syncthreads();
  }
  if (t < nN) rowStart[nodeLo + t] = lo + sc[t] - own;
  if (b == NBKT - 1 && t == 0) rowStart[N] = E;
  if (t < 512) sc[t] -= own;  // exclusive offsets become LDS cursors
  __syncthreads();
  for (int i = lo + t; i < hi; i += SORT_T) {
    int pk = __builtin_nontemporal_load(&epk[i]);
    int pos = lo + atomicAdd(&sc[pk >> 17], 1);
    colIdx[pos] = pk & 0x1FFFF;
  }
}

// ================= node transform: h = x@W (fp16), alphas (fp32) =================

template <int IN, int H, int C, bool NT>
__global__ void k_node(const float* __restrict__ xin, const float* __restrict__ W,
                       const float* __restrict__ a_src, const float* __restrict__ a_dst,
                       _Float16* __restrict__ hout, float* __restrict__ as_,
                       float* __restrict__ ad_, int N) {
  constexpr int OUT = H * C;
  __shared__ float Ws[IN * OUT];
  __shared__ float As[OUT], Ad[OUT];
  for (int i = threadIdx.x; i < IN * OUT; i += blockDim.x) Ws[i] = W[i];
  if (threadIdx.x < OUT) {
    As[threadIdx.x] = a_src[threadIdx.x];
    Ad[threadIdx.x] = a_dst[threadIdx.x];
  }
  __syncthreads();
  int n = blockIdx.x * blockDim.x + threadIdx.x;
  if (n >= N) return;
  float acc[OUT];
#pragma unroll
  for (int j = 0; j < OUT; ++j) acc[j] = 0.f;
  const f4v* x4 = reinterpret_cast<const f4v*>(xin + (size_t)n * IN);
#pragma unroll
  for (int k4 = 0; k4 < IN / 4; ++k4) {
    f4v xv = NT ? __builtin_nontemporal_load(&x4[k4]) : x4[k4];
#pragma unroll
    for (int j = 0; j < OUT; ++j) {
      acc[j] += xv[0] * Ws[(4 * k4 + 0) * OUT + j];
      acc[j] += xv[1] * Ws[(4 * k4 + 1) * OUT + j];
      acc[j] += xv[2] * Ws[(4 * k4 + 2) * OUT + j];
      acc[j] += xv[3] * Ws[(4 * k4 + 3) * OUT + j];
    }
  }
  h4v* h4 = reinterpret_cast<h4v*>(hout + (size_t)n * OUT);
#pragma unroll
  for (int j4 = 0; j4 < OUT / 4; ++j4) {
    h4v v;
    v[0] = (_Float16)acc[4 * j4 + 0];
    v[1] = (_Float16)acc[4 * j4 + 1];
    v[2] = (_Float16)acc[4 * j4 + 2];
    v[3] = (_Float16)acc[4 * j4 + 3];
    h4[j4] = v;
  }
#pragma unroll
  for (int hh = 0; hh < H; ++hh) {
    float ss = 0.f, dd = 0.f;
#pragma unroll
    for (int c = 0; c < C; ++c) {
      ss += acc[hh * C + c] * As[hh * C + c];
      dd += acc[hh * C + c] * Ad[hh * C + c];
    }
    as_[n * H + hh] = ss;
    ad_[n * H + hh] = dd;
  }
}

// ================= edge aggregation =================
// L feature-lanes x S edge-split sub-lanes per node; direct exp; shuffle combine.
// Batch-4 software pipeline: 4 colIdx loads, then 4 independent h/as gathers in
// flight, then compute -> one latency round-trip per 4 edges instead of per edge.

template <int H, int C, int L, int S, bool RELU>
__global__ void k_edge_ml(const int* __restrict__ rowStart, const int* __restrict__ colIdx,
                          const _Float16* __restrict__ hfeat, const float* __restrict__ as_,
                          const float* __restrict__ ad_, const float* __restrict__ bias,
                          float* __restrict__ out, int N, int R8) {
  constexpr int OUT = H * C;
  static_assert(OUT == L * 4, "lane layout");
  constexpr int LS = L * S;
  constexpr int NPB = TB / LS;
  const int g = blockIdx.x & (NGRP - 1);
  const int lb = blockIdx.x / NGRP;
  const int lane = threadIdx.x % LS;
  const int sub = lane / L;
  const int j = lane % L;
  const int n = g * R8 + lb * NPB + threadIdx.x / LS;
  const int nEnd = min((g + 1) * R8, N);
  if (n >= nEnd) return;
  const int hh = (j * 4) / C;
  const float adv = ad_[n * H + hh];
  const int start = rowStart[n];
  const int cnt = rowStart[n + 1] - start;
  const int lo = start + (cnt * sub) / S;
  const int hi = start + (cnt * (sub + 1)) / S;
  float s = 0.f, acc0 = 0.f, acc1 = 0.f, acc2 = 0.f, acc3 = 0.f;
  if (sub == 0) {  // self-loop
    float p = __expf(leaky(as_[n * H + hh] + adv));
    h4v a0 = reinterpret_cast<const h4v*>(hfeat + (size_t)n * OUT)[j];
    s = p;
    acc0 = p * (float)a0[0];
    acc1 = p * (float)a0[1];
    acc2 = p * (float)a0[2];
    acc3 = p * (float)a0[3];
  }
  int i = lo;
  for (; i + 4 <= hi; i += 4) {
    int s0 = colIdx[i + 0];
    int s1 = colIdx[i + 1];
    int s2 = colIdx[i + 2];
    int s3 = colIdx[i + 3];
    h4v v0 = reinterpret_cast<const h4v*>(hfeat + (size_t)s0 * OUT)[j];
    h4v v1 = reinterpret_cast<const h4v*>(hfeat + (size_t)s1 * OUT)[j];
    h4v v2 = reinterpret_cast<const h4v*>(hfeat + (size_t)s2 * OUT)[j];
    h4v v3 = reinterpret_cast<const h4v*>(hfeat + (size_t)s3 * OUT)[j];
    float e0 = as_[s0 * H + hh];
    float e1 = as_[s1 * H + hh];
    float e2 = as_[s2 * H + hh];
    float e3 = as_[s3 * H + hh];
    float p0 = __expf(leaky(e0 + adv));
    float p1 = __expf(leaky(e1 + adv));
    float p2 = __expf(leaky(e2 + adv));
    float p3 = __expf(leaky(e3 + adv));
    s += (p0 + p1) + (p2 + p3);
    acc0 += p0 * (float)v0[0] + p1 * (float)v1[0] + p2 * (float)v2[0] + p3 * (float)v3[0];
    acc1 += p0 * (float)v0[1] + p1 * (float)v1[1] + p2 * (float)v2[1] + p3 * (float)v3[1];
    acc2 += p0 * (float)v0[2] + p1 * (float)v1[2] + p2 * (float)v2[2] + p3 * (float)v3[2];
    acc3 += p0 * (float)v0[3] + p1 * (float)v1[3] + p2 * (float)v2[3] + p3 * (float)v3[3];
  }
  for (; i < hi; ++i) {
    int src = colIdx[i];
    h4v hv = reinterpret_cast<const h4v*>(hfeat + (size_t)src * OUT)[j];
    float p = __expf(leaky(as_[src * H + hh] + adv));
    s += p;
    acc0 += p * (float)hv[0];
    acc1 += p * (float)hv[1];
    acc2 += p * (float)hv[2];
    acc3 += p * (float)hv[3];
  }
#pragma unroll
  for (int off = L; off < LS; off <<= 1) {
    s += __shfl_xor(s, off);
    acc0 += __shfl_xor(acc0, off);
    acc1 += __shfl_xor(acc1, off);
    acc2 += __shfl_xor(acc2, off);
    acc3 += __shfl_xor(acc3, off);
  }
  if (sub == 0) {
    float inv = 1.f / (s + 1e-16f);
    float4 bb = reinterpret_cast<const float4*>(bias)[j];
    float4 o;
    o.x = acc0 * inv + bb.x;
    o.y = acc1 * inv + bb.y;
    o.z = acc2 * inv + bb.z;
    o.w = acc3 * inv + bb.w;
    if (RELU) {
      o.x = fmaxf(o.x, 0.f);
      o.y = fmaxf(o.y, 0.f);
      o.z = fmaxf(o.z, 0.f);
      o.w = fmaxf(o.w, 0.f);
    }
    reinterpret_cast<float4*>(out + (size_t)n * OUT)[j] = o;
  }
}

// layer-3 (H=1,C=4) edge aggregation + fused classifier; S=4 edge-split, batch-4
__global__ void k_edge3(const int* __restrict__ rowStart, const int* __restrict__ colIdx,
                        const _Float16* __restrict__ hfeat, const float* __restrict__ as_,
                        const float* __restrict__ ad_, const float* __restrict__ b3,
                        const float* __restrict__ Wc, const float* __restrict__ bc,
                        float* __restrict__ out, int N, int R8) {
  constexpr int S = 4;
  constexpr int NPB = TB / S;
  const int g = blockIdx.x & (NGRP - 1);
  const int lb = blockIdx.x / NGRP;
  const int sub = threadIdx.x % S;
  const int n = g * R8 + lb * NPB + threadIdx.x / S;
  const int nEnd = min((g + 1) * R8, N);
  if (n >= nEnd) return;
  const float adv = ad_[n];
  const int start = rowStart[n];
  const int cnt = rowStart[n + 1] - start;
  const int lo = start + (cnt * sub) / S;
  const int hi = start + (cnt * (sub + 1)) / S;
  float s = 0.f, acc0 = 0.f, acc1 = 0.f, acc2 = 0.f, acc3 = 0.f;
  if (sub == 0) {
    float p = __expf(leaky(as_[n] + adv));
    h4v a0 = reinterpret_cast<const h4v*>(hfeat)[n];
    s = p;
    acc0 = p * (float)a0[0];
    acc1 = p * (float)a0[1];
    acc2 = p * (float)a0[2];
    acc3 = p * (float)a0[3];
  }
  int i = lo;
  for (; i + 4 <= hi; i += 4) {
    int s0 = colIdx[i + 0];
    int s1 = colIdx[i + 1];
    int s2 = colIdx[i + 2];
    int s3 = colIdx[i + 3];
    h4v v0 = reinterpret_cast<const h4v*>(hfeat)[s0];
    h4v v1 = reinterpret_cast<const h4v*>(hfeat)[s1];
    h4v v2 = reinterpret_cast<const h4v*>(hfeat)[s2];
    h4v v3 = reinterpret_cast<const h4v*>(hfeat)[s3];
    float e0 = as_[s0];
    float e1 = as_[s1];
    float e2 = as_[s2];
    float e3 = as_[s3];
    float p0 = __expf(leaky(e0 + adv));
    float p1 = __expf(leaky(e1 + adv));
    float p2 = __expf(leaky(e2 + adv));
    float p3 = __expf(leaky(e3 + adv));
    s += (p0 + p1) + (p2 + p3);
    acc0 += p0 * (float)v0[0] + p1 * (float)v1[0] + p2 * (float)v2[0] + p3 * (float)v3[0];
    acc1 += p0 * (float)v0[1] + p1 * (float)v1[1] + p2 * (float)v2[1] + p3 * (float)v3[1];
    acc2 += p0 * (float)v0[2] + p1 * (float)v1[2] + p2 * (float)v2[2] + p3 * (float)v3[2];
    acc3 += p0 * (float)v0[3] + p1 * (float)v1[3] + p2 * (float)v2[3] + p3 * (float)v3[3];
  }
  for (; i < hi; ++i) {
    int src = colIdx[i];
    h4v hv = reinterpret_cast<const h4v*>(hfeat)[src];
    float p = __expf(leaky(as_[src] + adv));
    s += p;
    acc0 += p * (float)hv[0];
    acc1 += p * (float)hv[1];
    acc2 += p * (float)hv[2];
    acc3 += p * (float)hv[3];
  }
#pragma unroll
  for (int off = 1; off < S; off <<= 1) {
    s += __shfl_xor(s, off);
    acc0 += __shfl_xor(acc0, off);
    acc1 += __shfl_xor(acc1, off);
    acc2 += __shfl_xor(acc2, off);
    acc3 += __shfl_xor(acc3, off);
  }
  if (sub == 0) {
    float inv = 1.f / (s + 1e-16f);
    float o0 = acc0 * inv + b3[0];
    float o1 = acc1 * inv + b3[1];
    float o2 = acc2 * inv + b3[2];
    float o3 = acc3 * inv + b3[3];
    float2 r;
    r.x = o0 * Wc[0] + o1 * Wc[2] + o2 * Wc[4] + o3 * Wc[6] + bc[0];
    r.y = o0 * Wc[1] + o1 * Wc[3] + o2 * Wc[5] + o3 * Wc[7] + bc[1];
    reinterpret_cast<float2*>(out)[n] = r;
  }
}

// ================= launch =================

extern "C" void kernel_launch(void* const* d_in, const int* in_sizes, int n_in,
                              void* d_out, int out_size, void* d_ws, size_t ws_size,
                              hipStream_t stream) {
  const float* x    = (const float*)d_in[0];
  const int*   ei   = (const int*)d_in[1];
  const float* W1   = (const float*)d_in[2];
  const float* as1w = (const float*)d_in[3];
  const float* ad1w = (const float*)d_in[4];
  const float* b1   = (const float*)d_in[5];
  const float* W2   = (const float*)d_in[6];
  const float* as2w = (const float*)d_in[7];
  const float* ad2w = (const float*)d_in[8];
  const float* b2   = (const float*)d_in[9];
  const float* W3   = (const float*)d_in[10];
  const float* as3w = (const float*)d_in[11];
  const float* ad3w = (const float*)d_in[12];
  const float* b3   = (const float*)d_in[13];
  const float* Wc   = (const float*)d_in[14];
  const float* bc   = (const float*)d_in[15];
  float* out = (float*)d_out;

  const int N = in_sizes[0] / 128;
  const int E = in_sizes[1] / 2;
  const int* srcA = ei;
  const int* dstA = ei + E;

  char* p = (char*)d_ws;
  auto alloc = [&](size_t bytes) -> void* {
    void* r = (void*)p;
    p += (bytes + 255) & ~(size_t)255;
    return r;
  };
  int* cnt        = (int*)alloc((size_t)NBKT * NB_P * 4);
  int* off        = (int*)alloc((size_t)NBKT * NB_P * 4);
  int* colTotal   = (int*)alloc(NBKT * 4);
  int* bucketBase = (int*)alloc((NBKT + 1) * 4);
  int* rowStart   = (int*)alloc((size_t)(N + 1) * 4);
  int* epk        = (int*)alloc((size_t)E * 4);
  int* colIdx     = (int*)alloc((size_t)E * 4);
  _Float16* h1 = (_Float16*)alloc((size_t)N * 16 * 2);
  float* as1 = (float*)alloc((size_t)N * 2 * 4);
  float* ad1 = (float*)alloc((size_t)N * 2 * 4);
  float* o1  = (float*)alloc((size_t)N * 16 * 4);
  _Float16* h2 = (_Float16*)alloc((size_t)N * 8 * 2);
  float* as2 = (float*)alloc((size_t)N * 2 * 4);
  float* ad2 = (float*)alloc((size_t)N * 2 * 4);
  float* o2  = (float*)alloc((size_t)N * 8 * 4);
  _Float16* h3 = (_Float16*)alloc((size_t)N * 4 * 2);
  float* as3 = (float*)alloc((size_t)N * 4);
  float* ad3 = (float*)alloc((size_t)N * 4);

  const int R   = (N + NBKT - 1) / NBKT;                       // nodes per bucket (391)
  const unsigned M = (unsigned)(((1ULL << 32) + R - 1) / R);   // exact /R via __umulhi
  const int R8  = R * (NBKT / NGRP);                           // nodes per XCD (12512)
  const int E4  = E >> 2;
  const int CH4 = (E4 + NB_P - 1) / NB_P;
  const int nb  = (N + TB - 1) / TB;

  // CSR build (no global atomics)
  k_bcount<<<NB_P, TBP, 0, stream>>>(dstA, cnt, E4, E, M, CH4);
  k_bscan1<<<NBKT, NB_P, 0, stream>>>(cnt, off, colTotal);
  k_bscan2<<<1, NBKT, 0, stream>>>(colTotal, bucketBase);
  k_bscatter<<<NB_P, TBP, 0, stream>>>(srcA, dstA, off, bucketBase, epk, E4, E, M, R, CH4);
  k_bsort<<<NBKT, SORT_T, 0, stream>>>(epk, bucketBase, rowStart, colIdx, N, R, E);

  // edge-kernel grids: NGRP * ceil(R8 / nodes-per-block)
  const int g1 = NGRP * ((R8 + (TB / 8) - 1) / (TB / 8));   // L=4,S=2
  const int g2 = NGRP * ((R8 + (TB / 4) - 1) / (TB / 4));   // L=2,S=2
  const int g3 = NGRP * ((R8 + (TB / 4) - 1) / (TB / 4));   // S=4

  // layer 1: in=128, H=2, C=8
  k_node<128, 2, 8, true><<<nb, TB, 0, stream>>>(x, W1, as1w, ad1w, h1, as1, ad1, N);
  k_edge_ml<2, 8, 4, 2, true><<<g1, TB, 0, stream>>>(rowStart, colIdx, h1, as1, ad1, b1, o1, N, R8);

  // layer 2: in=16, H=2, C=4
  k_node<16, 2, 4, false><<<nb, TB, 0, stream>>>(o1, W2, as2w, ad2w, h2, as2, ad2, N);
  k_edge_ml<2, 4, 2, 2, true><<<g2, TB, 0, stream>>>(rowStart, colIdx, h2, as2, ad2, b2, o2, N, R8);

  // layer 3: in=8, H=1, C=4 + fused classifier
  k_node<8, 1, 4, false><<<nb, TB, 0, stream>>>(o2, W3, as3w, ad3w, h3, as3, ad3, N);
  k_edge3<<<g3, TB, 0, stream>>>(rowStart, colIdx, h3, as3, ad3, b3, Wc, bc, out, N, R8);
}

// Round 7
// 215.009 us; speedup vs baseline: 2.7927x; 1.0661x over previous
//
#include <hip/hip_runtime.h>

#define TB 256
#define NGRP 8            // XCDs on MI355X; blockIdx%8 round-robins across XCDs
#define NB_P 256          // partition blocks
#define TBP 256           // partition block threads
#define NBKT 256          // dst-range buckets (32 per XCD)
#define SORT_T 1024

typedef int      i4v __attribute__((ext_vector_type(4)));
typedef float    f4v __attribute__((ext_vector_type(4)));
typedef _Float16 h4v __attribute__((ext_vector_type(4)));

static __device__ __forceinline__ float leaky(float x) {
  return x > 0.f ? x : 0.2f * x;
}

// ================= CSR build: 256-bucket partition + per-bucket LDS sort =================

// A1: per-block bucket counts (LDS), cnt laid out [bucket][block] for coalesced scan.
__global__ void k_bcount(const int* __restrict__ dstA, int* __restrict__ cnt,
                         int E4, int E, unsigned M, int CH4) {
  __shared__ int lc[NBKT];
  for (int i = threadIdx.x; i < NBKT; i += TBP) lc[i] = 0;
  __syncthreads();
  const int bstart = blockIdx.x * CH4;
  const int bend = min(E4, bstart + CH4);
  const i4v* d4 = reinterpret_cast<const i4v*>(dstA);
  for (int i = bstart + threadIdx.x; i < bend; i += TBP) {
    i4v d = __builtin_nontemporal_load(&d4[i]);
#pragma unroll
    for (int k = 0; k < 4; ++k) atomicAdd(&lc[__umulhi((unsigned)d[k], M)], 1);
  }
  if (blockIdx.x == NB_P - 1) {
    for (int t = E4 * 4 + threadIdx.x; t < E; t += TBP)
      atomicAdd(&lc[__umulhi((unsigned)dstA[t], M)], 1);
  }
  __syncthreads();
  for (int b = threadIdx.x; b < NBKT; b += TBP) cnt[b * NB_P + blockIdx.x] = lc[b];
}

// A2a: per-bucket exclusive scan over blocks (grid = NBKT, block = NB_P threads).
__global__ void k_bscan1(const int* __restrict__ cnt, int* __restrict__ off,
                         int* __restrict__ colTotal) {
  __shared__ int sh[NB_P];
  const int t = threadIdx.x;
  const int b = blockIdx.x;
  int v = cnt[b * NB_P + t];
  sh[t] = v;
  __syncthreads();
  for (int o = 1; o < NB_P; o <<= 1) {
    int u = (t >= o) ? sh[t - o] : 0;
    __syncthreads();
    sh[t] += u;
    __syncthreads();
  }
  off[b * NB_P + t] = sh[t] - v;
  if (t == NB_P - 1) colTotal[b] = sh[t];
}

// A2b: exclusive scan of bucket totals -> bucketBase[NBKT+1].
__global__ void k_bscan2(const int* __restrict__ colTotal, int* __restrict__ bucketBase) {
  __shared__ int sh[NBKT];
  const int t = threadIdx.x;
  int v = colTotal[t];
  sh[t] = v;
  __syncthreads();
  for (int o = 1; o < NBKT; o <<= 1) {
    int u = (t >= o) ? sh[t - o] : 0;
    __syncthreads();
    sh[t] += u;
    __syncthreads();
  }
  bucketBase[t] = sh[t] - v;
  if (t == NBKT - 1) bucketBase[NBKT] = sh[t];
}

// A3: scatter packed (dloc<<17 | src) into bucket segments via LDS cursors.
__global__ void k_bscatter(const int* __restrict__ srcA, const int* __restrict__ dstA,
                           const int* __restrict__ off, const int* __restrict__ bucketBase,
                           int* __restrict__ epk, int E4, int E, unsigned M, int R, int CH4) {
  __shared__ int lcur[NBKT];
  for (int i = threadIdx.x; i < NBKT; i += TBP)
    lcur[i] = bucketBase[i] + off[i * NB_P + blockIdx.x];
  __syncthreads();
  const int bstart = blockIdx.x * CH4;
  const int bend = min(E4, bstart + CH4);
  const i4v* d4 = reinterpret_cast<const i4v*>(dstA);
  const i4v* s4 = reinterpret_cast<const i4v*>(srcA);
  for (int i = bstart + threadIdx.x; i < bend; i += TBP) {
    i4v d = __builtin_nontemporal_load(&d4[i]);
    i4v sv = __builtin_nontemporal_load(&s4[i]);
#pragma unroll
    for (int k = 0; k < 4; ++k) {
      int dd = d[k];
      int b = __umulhi((unsigned)dd, M);
      int pos = atomicAdd(&lcur[b], 1);
      epk[pos] = ((dd - b * R) << 17) | sv[k];
    }
  }
  if (blockIdx.x == NB_P - 1) {
    for (int t = E4 * 4 + threadIdx.x; t < E; t += TBP) {
      int dd = dstA[t];
      int b = __umulhi((unsigned)dd, M);
      int pos = atomicAdd(&lcur[b], 1);
      epk[pos] = ((dd - b * R) << 17) | srcA[t];
    }
  }
}

// B: per-bucket counting sort in LDS -> rowStart slice + colIdx segment.
// Bucket b mapped so XCD g = b/32 processes its own node range.
__global__ void k_bsort(const int* __restrict__ epk, const int* __restrict__ bucketBase,
                        int* __restrict__ rowStart, int* __restrict__ colIdx,
                        int N, int R, int E) {
  __shared__ int sc[512];
  const int b = (blockIdx.x & (NGRP - 1)) * (NBKT / NGRP) + (blockIdx.x >> 3);
  const int lo = bucketBase[b], hi = bucketBase[b + 1];
  const int nodeLo = b * R;
  const int nN = min(R, N - nodeLo);
  const int t = threadIdx.x;
  if (t < 512) sc[t] = 0;
  __syncthreads();
  for (int i = lo + t; i < hi; i += SORT_T) {
    int pk = __builtin_nontemporal_load(&epk[i]);
    atomicAdd(&sc[pk >> 17], 1);
  }
  __syncthreads();
  int own = (t < 512) ? sc[t] : 0;
  for (int o = 1; o < 512; o <<= 1) {
    int u = (t < 512 && t >= o) ? sc[t - o] : 0;
    __syncthreads();
    if (t < 512) sc[t] += u;
    __syncthreads();
  }
  if (t < nN) rowStart[nodeLo + t] = lo + sc[t] - own;
  if (b == NBKT - 1 && t == 0) rowStart[N] = E;
  if (t < 512) sc[t] -= own;  // exclusive offsets become LDS cursors
  __syncthreads();
  for (int i = lo + t; i < hi; i += SORT_T) {
    int pk = __builtin_nontemporal_load(&epk[i]);
    int pos = lo + atomicAdd(&sc[pk >> 17], 1);
    colIdx[pos] = pk & 0x1FFFF;
  }
}

// ================= node transform: SPLIT threads/node, shuffle-combined =================
// Lane j of a node loads IN/SPLIT contiguous floats (inter-lane stride IN/SPLIT*4 B),
// computes partial acc[OUT], xor-butterfly gives all SPLIT lanes the full row.
// Lane j < OUT/4 writes h4v chunk j; lanes hh < H write alphas.

template <int IN, int H, int C, int SPLIT, bool NT>
__global__ void k_node(const float* __restrict__ xin, const float* __restrict__ W,
                       const float* __restrict__ a_src, const float* __restrict__ a_dst,
                       _Float16* __restrict__ hout, float* __restrict__ as_,
                       float* __restrict__ ad_, int N) {
  constexpr int OUT = H * C;
  constexpr int PIN4 = IN / SPLIT / 4;   // float4 loads per thread
  constexpr int NPB = TB / SPLIT;
  __shared__ float Ws[IN * OUT];
  __shared__ float As[OUT], Ad[OUT];
  for (int i = threadIdx.x; i < IN * OUT; i += blockDim.x) Ws[i] = W[i];
  if (threadIdx.x < OUT) {
    As[threadIdx.x] = a_src[threadIdx.x];
    Ad[threadIdx.x] = a_dst[threadIdx.x];
  }
  __syncthreads();
  const int j = threadIdx.x & (SPLIT - 1);
  const int n = blockIdx.x * NPB + threadIdx.x / SPLIT;
  if (n >= N) return;
  float acc[OUT];
#pragma unroll
  for (int q = 0; q < OUT; ++q) acc[q] = 0.f;
  const f4v* x4 = reinterpret_cast<const f4v*>(xin + (size_t)n * IN + j * (IN / SPLIT));
#pragma unroll
  for (int k4 = 0; k4 < PIN4; ++k4) {
    f4v xv = NT ? __builtin_nontemporal_load(&x4[k4]) : x4[k4];
    const int kb = j * (IN / SPLIT) + 4 * k4;
#pragma unroll
    for (int q = 0; q < OUT; ++q) {
      acc[q] += xv[0] * Ws[(kb + 0) * OUT + q];
      acc[q] += xv[1] * Ws[(kb + 1) * OUT + q];
      acc[q] += xv[2] * Ws[(kb + 2) * OUT + q];
      acc[q] += xv[3] * Ws[(kb + 3) * OUT + q];
    }
  }
#pragma unroll
  for (int o = 1; o < SPLIT; o <<= 1) {
#pragma unroll
    for (int q = 0; q < OUT; ++q) acc[q] += __shfl_xor(acc[q], o);
  }
  constexpr int WCH = OUT / 4;  // h4v chunks (WCH <= SPLIT guaranteed by instantiation)
  if (j < WCH) {
    h4v v;
    v[0] = (_Float16)acc[4 * j + 0];
    v[1] = (_Float16)acc[4 * j + 1];
    v[2] = (_Float16)acc[4 * j + 2];
    v[3] = (_Float16)acc[4 * j + 3];
    reinterpret_cast<h4v*>(hout + (size_t)n * OUT)[j] = v;
  }
  if (j < H) {
    float ss = 0.f, dd = 0.f;
#pragma unroll
    for (int c = 0; c < C; ++c) {
      ss += acc[j * C + c] * As[j * C + c];
      dd += acc[j * C + c] * Ad[j * C + c];
    }
    as_[n * H + j] = ss;
    ad_[n * H + j] = dd;
  }
}

// ================= edge aggregation =================
// L feature-lanes x S edge-split sub-lanes per node; direct exp; shuffle combine.
// Batch-4 software pipeline for memory-level parallelism.

template <int H, int C, int L, int S, bool RELU>
__global__ void k_edge_ml(const int* __restrict__ rowStart, const int* __restrict__ colIdx,
                          const _Float16* __restrict__ hfeat, const float* __restrict__ as_,
                          const float* __restrict__ ad_, const float* __restrict__ bias,
                          float* __restrict__ out, int N, int R8) {
  constexpr int OUT = H * C;
  static_assert(OUT == L * 4, "lane layout");
  constexpr int LS = L * S;
  constexpr int NPB = TB / LS;
  const int g = blockIdx.x & (NGRP - 1);
  const int lb = blockIdx.x / NGRP;
  const int lane = threadIdx.x % LS;
  const int sub = lane / L;
  const int j = lane % L;
  const int n = g * R8 + lb * NPB + threadIdx.x / LS;
  const int nEnd = min((g + 1) * R8, N);
  if (n >= nEnd) return;
  const int hh = (j * 4) / C;
  const float adv = ad_[n * H + hh];
  const int start = rowStart[n];
  const int cnt = rowStart[n + 1] - start;
  const int lo = start + (cnt * sub) / S;
  const int hi = start + (cnt * (sub + 1)) / S;
  float s = 0.f, acc0 = 0.f, acc1 = 0.f, acc2 = 0.f, acc3 = 0.f;
  if (sub == 0) {  // self-loop
    float p = __expf(leaky(as_[n * H + hh] + adv));
    h4v a0 = reinterpret_cast<const h4v*>(hfeat + (size_t)n * OUT)[j];
    s = p;
    acc0 = p * (float)a0[0];
    acc1 = p * (float)a0[1];
    acc2 = p * (float)a0[2];
    acc3 = p * (float)a0[3];
  }
  int i = lo;
  for (; i + 4 <= hi; i += 4) {
    int s0 = colIdx[i + 0];
    int s1 = colIdx[i + 1];
    int s2 = colIdx[i + 2];
    int s3 = colIdx[i + 3];
    h4v v0 = reinterpret_cast<const h4v*>(hfeat + (size_t)s0 * OUT)[j];
    h4v v1 = reinterpret_cast<const h4v*>(hfeat + (size_t)s1 * OUT)[j];
    h4v v2 = reinterpret_cast<const h4v*>(hfeat + (size_t)s2 * OUT)[j];
    h4v v3 = reinterpret_cast<const h4v*>(hfeat + (size_t)s3 * OUT)[j];
    float e0 = as_[s0 * H + hh];
    float e1 = as_[s1 * H + hh];
    float e2 = as_[s2 * H + hh];
    float e3 = as_[s3 * H + hh];
    float p0 = __expf(leaky(e0 + adv));
    float p1 = __expf(leaky(e1 + adv));
    float p2 = __expf(leaky(e2 + adv));
    float p3 = __expf(leaky(e3 + adv));
    s += (p0 + p1) + (p2 + p3);
    acc0 += p0 * (float)v0[0] + p1 * (float)v1[0] + p2 * (float)v2[0] + p3 * (float)v3[0];
    acc1 += p0 * (float)v0[1] + p1 * (float)v1[1] + p2 * (float)v2[1] + p3 * (float)v3[1];
    acc2 += p0 * (float)v0[2] + p1 * (float)v1[2] + p2 * (float)v2[2] + p3 * (float)v3[2];
    acc3 += p0 * (float)v0[3] + p1 * (float)v1[3] + p2 * (float)v2[3] + p3 * (float)v3[3];
  }
  for (; i < hi; ++i) {
    int src = colIdx[i];
    h4v hv = reinterpret_cast<const h4v*>(hfeat + (size_t)src * OUT)[j];
    float p = __expf(leaky(as_[src * H + hh] + adv));
    s += p;
    acc0 += p * (float)hv[0];
    acc1 += p * (float)hv[1];
    acc2 += p * (float)hv[2];
    acc3 += p * (float)hv[3];
  }
#pragma unroll
  for (int off = L; off < LS; off <<= 1) {
    s += __shfl_xor(s, off);
    acc0 += __shfl_xor(acc0, off);
    acc1 += __shfl_xor(acc1, off);
    acc2 += __shfl_xor(acc2, off);
    acc3 += __shfl_xor(acc3, off);
  }
  if (sub == 0) {
    float inv = 1.f / (s + 1e-16f);
    float4 bb = reinterpret_cast<const float4*>(bias)[j];
    float4 o;
    o.x = acc0 * inv + bb.x;
    o.y = acc1 * inv + bb.y;
    o.z = acc2 * inv + bb.z;
    o.w = acc3 * inv + bb.w;
    if (RELU) {
      o.x = fmaxf(o.x, 0.f);
      o.y = fmaxf(o.y, 0.f);
      o.z = fmaxf(o.z, 0.f);
      o.w = fmaxf(o.w, 0.f);
    }
    reinterpret_cast<float4*>(out + (size_t)n * OUT)[j] = o;
  }
}

// layer-3 (H=1,C=4) edge aggregation + fused classifier; S=8 edge-split, batch-4
__global__ void k_edge3(const int* __restrict__ rowStart, const int* __restrict__ colIdx,
                        const _Float16* __restrict__ hfeat, const float* __restrict__ as_,
                        const float* __restrict__ ad_, const float* __restrict__ b3,
                        const float* __restrict__ Wc, const float* __restrict__ bc,
                        float* __restrict__ out, int N, int R8) {
  constexpr int S = 8;
  constexpr int NPB = TB / S;
  const int g = blockIdx.x & (NGRP - 1);
  const int lb = blockIdx.x / NGRP;
  const int sub = threadIdx.x % S;
  const int n = g * R8 + lb * NPB + threadIdx.x / S;
  const int nEnd = min((g + 1) * R8, N);
  if (n >= nEnd) return;
  const float adv = ad_[n];
  const int start = rowStart[n];
  const int cnt = rowStart[n + 1] - start;
  const int lo = start + (cnt * sub) / S;
  const int hi = start + (cnt * (sub + 1)) / S;
  float s = 0.f, acc0 = 0.f, acc1 = 0.f, acc2 = 0.f, acc3 = 0.f;
  if (sub == 0) {
    float p = __expf(leaky(as_[n] + adv));
    h4v a0 = reinterpret_cast<const h4v*>(hfeat)[n];
    s = p;
    acc0 = p * (float)a0[0];
    acc1 = p * (float)a0[1];
    acc2 = p * (float)a0[2];
    acc3 = p * (float)a0[3];
  }
  int i = lo;
  for (; i + 4 <= hi; i += 4) {
    int s0 = colIdx[i + 0];
    int s1 = colIdx[i + 1];
    int s2 = colIdx[i + 2];
    int s3 = colIdx[i + 3];
    h4v v0 = reinterpret_cast<const h4v*>(hfeat)[s0];
    h4v v1 = reinterpret_cast<const h4v*>(hfeat)[s1];
    h4v v2 = reinterpret_cast<const h4v*>(hfeat)[s2];
    h4v v3 = reinterpret_cast<const h4v*>(hfeat)[s3];
    float e0 = as_[s0];
    float e1 = as_[s1];
    float e2 = as_[s2];
    float e3 = as_[s3];
    float p0 = __expf(leaky(e0 + adv));
    float p1 = __expf(leaky(e1 + adv));
    float p2 = __expf(leaky(e2 + adv));
    float p3 = __expf(leaky(e3 + adv));
    s += (p0 + p1) + (p2 + p3);
    acc0 += p0 * (float)v0[0] + p1 * (float)v1[0] + p2 * (float)v2[0] + p3 * (float)v3[0];
    acc1 += p0 * (float)v0[1] + p1 * (float)v1[1] + p2 * (float)v2[1] + p3 * (float)v3[1];
    acc2 += p0 * (float)v0[2] + p1 * (float)v1[2] + p2 * (float)v2[2] + p3 * (float)v3[2];
    acc3 += p0 * (float)v0[3] + p1 * (float)v1[3] + p2 * (float)v2[3] + p3 * (float)v3[3];
  }
  for (; i < hi; ++i) {
    int src = colIdx[i];
    h4v hv = reinterpret_cast<const h4v*>(hfeat)[src];
    float p = __expf(leaky(as_[src] + adv));
    s += p;
    acc0 += p * (float)hv[0];
    acc1 += p * (float)hv[1];
    acc2 += p * (float)hv[2];
    acc3 += p * (float)hv[3];
  }
#pragma unroll
  for (int off = 1; off < S; off <<= 1) {
    s += __shfl_xor(s, off);
    acc0 += __shfl_xor(acc0, off);
    acc1 += __shfl_xor(acc1, off);
    acc2 += __shfl_xor(acc2, off);
    acc3 += __shfl_xor(acc3, off);
  }
  if (sub == 0) {
    float inv = 1.f / (s + 1e-16f);
    float o0 = acc0 * inv + b3[0];
    float o1 = acc1 * inv + b3[1];
    float o2 = acc2 * inv + b3[2];
    float o3 = acc3 * inv + b3[3];
    float2 r;
    r.x = o0 * Wc[0] + o1 * Wc[2] + o2 * Wc[4] + o3 * Wc[6] + bc[0];
    r.y = o0 * Wc[1] + o1 * Wc[3] + o2 * Wc[5] + o3 * Wc[7] + bc[1];
    reinterpret_cast<float2*>(out)[n] = r;
  }
}

// ================= launch =================

extern "C" void kernel_launch(void* const* d_in, const int* in_sizes, int n_in,
                              void* d_out, int out_size, void* d_ws, size_t ws_size,
                              hipStream_t stream) {
  const float* x    = (const float*)d_in[0];
  const int*   ei   = (const int*)d_in[1];
  const float* W1   = (const float*)d_in[2];
  const float* as1w = (const float*)d_in[3];
  const float* ad1w = (const float*)d_in[4];
  const float* b1   = (const float*)d_in[5];
  const float* W2   = (const float*)d_in[6];
  const float* as2w = (const float*)d_in[7];
  const float* ad2w = (const float*)d_in[8];
  const float* b2   = (const float*)d_in[9];
  const float* W3   = (const float*)d_in[10];
  const float* as3w = (const float*)d_in[11];
  const float* ad3w = (const float*)d_in[12];
  const float* b3   = (const float*)d_in[13];
  const float* Wc   = (const float*)d_in[14];
  const float* bc   = (const float*)d_in[15];
  float* out = (float*)d_out;

  const int N = in_sizes[0] / 128;
  const int E = in_sizes[1] / 2;
  const int* srcA = ei;
  const int* dstA = ei + E;

  char* p = (char*)d_ws;
  auto alloc = [&](size_t bytes) -> void* {
    void* r = (void*)p;
    p += (bytes + 255) & ~(size_t)255;
    return r;
  };
  int* cnt        = (int*)alloc((size_t)NBKT * NB_P * 4);
  int* off        = (int*)alloc((size_t)NBKT * NB_P * 4);
  int* colTotal   = (int*)alloc(NBKT * 4);
  int* bucketBase = (int*)alloc((NBKT + 1) * 4);
  int* rowStart   = (int*)alloc((size_t)(N + 1) * 4);
  int* epk        = (int*)alloc((size_t)E * 4);
  int* colIdx     = (int*)alloc((size_t)E * 4);
  _Float16* h1 = (_Float16*)alloc((size_t)N * 16 * 2);
  float* as1 = (float*)alloc((size_t)N * 2 * 4);
  float* ad1 = (float*)alloc((size_t)N * 2 * 4);
  float* o1  = (float*)alloc((size_t)N * 16 * 4);
  _Float16* h2 = (_Float16*)alloc((size_t)N * 8 * 2);
  float* as2 = (float*)alloc((size_t)N * 2 * 4);
  float* ad2 = (float*)alloc((size_t)N * 2 * 4);
  float* o2  = (float*)alloc((size_t)N * 8 * 4);
  _Float16* h3 = (_Float16*)alloc((size_t)N * 4 * 2);
  float* as3 = (float*)alloc((size_t)N * 4);
  float* ad3 = (float*)alloc((size_t)N * 4);

  const int R   = (N + NBKT - 1) / NBKT;                       // nodes per bucket (391)
  const unsigned M = (unsigned)(((1ULL << 32) + R - 1) / R);   // exact /R via __umulhi
  const int R8  = R * (NBKT / NGRP);                           // nodes per XCD (12512)
  const int E4  = E >> 2;
  const int CH4 = (E4 + NB_P - 1) / NB_P;

  // CSR build (no global atomics)
  k_bcount<<<NB_P, TBP, 0, stream>>>(dstA, cnt, E4, E, M, CH4);
  k_bscan1<<<NBKT, NB_P, 0, stream>>>(cnt, off, colTotal);
  k_bscan2<<<1, NBKT, 0, stream>>>(colTotal, bucketBase);
  k_bscatter<<<NB_P, TBP, 0, stream>>>(srcA, dstA, off, bucketBase, epk, E4, E, M, R, CH4);
  k_bsort<<<NBKT, SORT_T, 0, stream>>>(epk, bucketBase, rowStart, colIdx, N, R, E);

  // node-kernel grids: ceil(N / (TB/SPLIT))
  const int nb1 = (N + (TB / 4) - 1) / (TB / 4);
  const int nb2 = (N + (TB / 2) - 1) / (TB / 2);
  // edge-kernel grids: NGRP * ceil(R8 / nodes-per-block)
  const int g1 = NGRP * ((R8 + (TB / 16) - 1) / (TB / 16));  // L=4,S=4
  const int g2 = NGRP * ((R8 + (TB / 8) - 1) / (TB / 8));    // L=2,S=4
  const int g3 = NGRP * ((R8 + (TB / 8) - 1) / (TB / 8));    // S=8

  // layer 1: in=128, H=2, C=8
  k_node<128, 2, 8, 4, true><<<nb1, TB, 0, stream>>>(x, W1, as1w, ad1w, h1, as1, ad1, N);
  k_edge_ml<2, 8, 4, 4, true><<<g1, TB, 0, stream>>>(rowStart, colIdx, h1, as1, ad1, b1, o1, N, R8);

  // layer 2: in=16, H=2, C=4
  k_node<16, 2, 4, 2, false><<<nb2, TB, 0, stream>>>(o1, W2, as2w, ad2w, h2, as2, ad2, N);
  k_edge_ml<2, 4, 2, 4, true><<<g2, TB, 0, stream>>>(rowStart, colIdx, h2, as2, ad2, b2, o2, N, R8);

  // layer 3: in=8, H=1, C=4 + fused classifier
  k_node<8, 1, 4, 2, false><<<nb2, TB, 0, stream>>>(o2, W3, as3w, ad3w, h3, as3, ad3, N);
  k_edge3<<<g3, TB, 0, stream>>>(rowStart, colIdx, h3, as3, ad3, b3, Wc, bc, out, N, R8);
}